// Round 1
// baseline (534.801 us; speedup 1.0000x reference)
//
#include <hip/hip_runtime.h>
#include <cstdint>

// Problem constants (fixed by reference: B=4, S=2048)
#define TOK  8192   // B*S
#define DEMB 1024   // N_EMBD
#define HID  4096   // HIDDEN
#define ADP  256    // ADAPT
#define NEXP 8

typedef __bf16 bf16x8 __attribute__((ext_vector_type(8)));
typedef float  f32x4  __attribute__((ext_vector_type(4)));

__device__ __forceinline__ unsigned short f2bf(float f) {
  // round-to-nearest-even fp32 -> bf16 (matches numpy/jax cast for normal values)
  unsigned int u = __float_as_uint(f);
  u += 0x7fffu + ((u >> 16) & 1u);
  return (unsigned short)(u >> 16);
}
__device__ __forceinline__ float bf2f(unsigned short b) {
  return __uint_as_float(((unsigned int)b) << 16);
}

// ---------------------------------------------------------------------------
// fp32 -> bf16 conversion for x and all weight tensors, one kernel.
// Each block converts 2048 contiguous elements (256 thr x 2 x float4).
// ---------------------------------------------------------------------------
__global__ __launch_bounds__(256) void convert_all(
    const float* __restrict__ x, const float* __restrict__ wup,
    const float* __restrict__ wout, const float* __restrict__ wadapt,
    const float* __restrict__ wexp, const float* __restrict__ wproj,
    unsigned short* __restrict__ xb, unsigned short* __restrict__ wub,
    unsigned short* __restrict__ wob, unsigned short* __restrict__ wab,
    unsigned short* __restrict__ web, unsigned short* __restrict__ wpb) {
  int b = blockIdx.x;
  const float* src; unsigned short* dst; int lb;
  if      (b < 4096) { src = x;      dst = xb;  lb = b; }
  else if (b < 6144) { src = wup;    dst = wub; lb = b - 4096; }
  else if (b < 8192) { src = wout;   dst = wob; lb = b - 6144; }
  else if (b < 8704) { src = wadapt; dst = wab; lb = b - 8192; }
  else if (b < 8960) { src = wexp;   dst = web; lb = b - 8704; }
  else               { src = wproj;  dst = wpb; lb = b - 8960; }
  size_t base = (size_t)lb * 2048;
#pragma unroll
  for (int h = 0; h < 2; ++h) {
    size_t off = base + (size_t)h * 1024 + (size_t)threadIdx.x * 4;
    float4 v = *(const float4*)(src + off);
    ushort4 o;
    o.x = f2bf(v.x); o.y = f2bf(v.y); o.z = f2bf(v.z); o.w = f2bf(v.w);
    *(ushort4*)(dst + off) = o;
  }
}

// ---------------------------------------------------------------------------
// Routing: last active expert index per token (-1 if none).
// ---------------------------------------------------------------------------
__global__ __launch_bounds__(256) void route_kernel(const float* __restrict__ ew,
                                                    int* __restrict__ route) {
  int t = blockIdx.x * 256 + threadIdx.x;
  const float* p = ew + (size_t)t * NEXP;
  int r = -1;
#pragma unroll
  for (int e = 0; e < NEXP; ++e)
    if (p[e] > 0.f) r = e;
  route[t] = r;
}

// ---------------------------------------------------------------------------
// 128x128x(BK=64) bf16 MFMA GEMM, C[m,n] = sum_k A[m,k]*B[n,k]  (B^T layout).
// m97 structure: global_load_lds width-16 staging, XOR-swizzled LDS (kills
// ds_read_b128 bank conflicts), 4 waves in 2x2 grid, 4x4 16x16x32 tiles/wave.
// EPI: 0 = silu -> bf16, 1 = fp32 store (+split-K offset), 2 = in-place
//      bf16 C := C + 0.1*act(row)*acc.
// ---------------------------------------------------------------------------
__device__ __forceinline__ void stage_tile(const unsigned short* __restrict__ g,
                                           int ldg, unsigned short* lds,
                                           int wave, int lane) {
  // tile = 128 rows x 64 cols bf16; 16 chunks of 8 rows; wave stages 4 chunks.
  // LDS dst for lane i is base + i*16B (wave-uniform base semantics), i.e.
  // row = chunk*8 + i/8, k-block = i%8. Source column is XOR-swizzled so the
  // LDS image holds (m, kb^ (m&7)) -> conflict-free ds_read_b128 later.
  int srow = lane >> 3;
  int scol = ((lane & 7) ^ (srow & 7)) * 8;
#pragma unroll
  for (int c = 0; c < 4; ++c) {
    int chunk = wave * 4 + c;
    const unsigned short* gp = g + (size_t)(chunk * 8 + srow) * ldg + scol;
    unsigned short* lp = lds + chunk * 512;
    __builtin_amdgcn_global_load_lds(
        (const __attribute__((address_space(1))) unsigned int*)(uintptr_t)gp,
        (__attribute__((address_space(3))) unsigned int*)(uintptr_t)lp,
        16, 0, 0);
  }
}

template <int EPI>
__global__ __launch_bounds__(256) void gemm128(
    const unsigned short* __restrict__ A, int lda,
    const unsigned short* __restrict__ B, int ldb,
    void* __restrict__ C, int ldc,
    const int* __restrict__ route, int kLen, long splitStride) {
  __shared__ unsigned short As[128 * 64];
  __shared__ unsigned short Bs[128 * 64];
  const int lane = threadIdx.x & 63;
  const int wave = threadIdx.x >> 6;
  const int wm = wave >> 1, wn = wave & 1;
  const long rowBase = (long)blockIdx.y * 128;
  const long colBase = (long)blockIdx.x * 128;
  const int ks = blockIdx.z * kLen;
  const unsigned short* Ap = A + rowBase * lda + ks;
  const unsigned short* Bp = B + colBase * ldb + ks;
  f32x4 acc[4][4] = {};

  for (int kt = 0; kt < kLen; kt += 64) {
    stage_tile(Ap + kt, lda, As, wave, lane);
    stage_tile(Bp + kt, ldb, Bs, wave, lane);
    __syncthreads();
#pragma unroll
    for (int kk = 0; kk < 64; kk += 32) {
      const int kb = (kk >> 3) + (lane >> 4);   // k-block 0..7
      const int sw = kb ^ (lane & 7);           // swizzled k-block
      bf16x8 af[4], bfr[4];
#pragma unroll
      for (int mt = 0; mt < 4; ++mt) {
        int m = wm * 64 + mt * 16 + (lane & 15);
        af[mt] = *(const bf16x8*)&As[m * 64 + sw * 8];
      }
#pragma unroll
      for (int nt = 0; nt < 4; ++nt) {
        int n = wn * 64 + nt * 16 + (lane & 15);
        bfr[nt] = *(const bf16x8*)&Bs[n * 64 + sw * 8];
      }
#pragma unroll
      for (int mt = 0; mt < 4; ++mt)
#pragma unroll
        for (int nt = 0; nt < 4; ++nt)
          acc[mt][nt] = __builtin_amdgcn_mfma_f32_16x16x32_bf16(
              af[mt], bfr[nt], acc[mt][nt], 0, 0, 0);
    }
    __syncthreads();
  }

  // Epilogue. C/D layout (m89-verified): col = lane&15, row = (lane>>4)*4 + r.
  const int rsub = (lane >> 4) * 4;
  const int csub = lane & 15;
#pragma unroll
  for (int mt = 0; mt < 4; ++mt) {
#pragma unroll
    for (int nt = 0; nt < 4; ++nt) {
      long col = colBase + wn * 64 + nt * 16 + csub;
#pragma unroll
      for (int r = 0; r < 4; ++r) {
        long row = rowBase + wm * 64 + mt * 16 + rsub + r;
        float v = acc[mt][nt][r];
        if (EPI == 0) {
          float s = __fdividef(v, 1.0f + __expf(-v));  // silu
          ((unsigned short*)C)[row * ldc + col] = f2bf(s);
        } else if (EPI == 1) {
          ((float*)C + splitStride * blockIdx.z)[row * ldc + col] = v;
        } else {
          long idx = row * ldc + col;
          float h = bf2f(((unsigned short*)C)[idx]);
          float sc = (route[row] >= 0) ? 0.1f : 0.0f;
          ((unsigned short*)C)[idx] = f2bf(h + sc * v);
        }
      }
    }
  }
}

// ---------------------------------------------------------------------------
// Per-token expert adapter (256x256 matvec) + LayerNorm.
// 16 tokens per block; thread o computes output element o.
// Sums the 4 split-K partials of A on load. W_exp is L2-resident (1 MB bf16).
// ---------------------------------------------------------------------------
__global__ __launch_bounds__(256) void adapter_ln(
    const float* __restrict__ P,            // [4][TOK][ADP] fp32 partials
    const unsigned short* __restrict__ Wexp,// [8][256][256] bf16
    const int* __restrict__ route,
    const float* __restrict__ gamma, const float* __restrict__ beta,
    unsigned short* __restrict__ anorm) {
  __shared__ float sA[ADP];
  __shared__ float redS[4], redQ[4];
  __shared__ float sMu, sRstd;
  const int tid = threadIdx.x;
  const int lane = tid & 63, wv = tid >> 6;
  for (int tt = 0; tt < 16; ++tt) {
    int t = blockIdx.x * 16 + tt;
    size_t ti = (size_t)t * ADP + tid;
    float a = P[ti] + P[(size_t)TOK * ADP + ti] + P[2 * (size_t)TOK * ADP + ti] +
              P[3 * (size_t)TOK * ADP + ti];
    int e = route[t];
    __syncthreads();            // previous iteration fully done with sA
    sA[tid] = a;
    __syncthreads();
    float dot = 0.f;
    if (e >= 0) {
      const unsigned short* w = Wexp + ((size_t)e * ADP + tid) * ADP;
#pragma unroll 4
      for (int d = 0; d < ADP; d += 8) {
        uint4 u = *(const uint4*)(w + d);
        dot += sA[d + 0] * bf2f((unsigned short)u.x) +
               sA[d + 1] * bf2f((unsigned short)(u.x >> 16)) +
               sA[d + 2] * bf2f((unsigned short)u.y) +
               sA[d + 3] * bf2f((unsigned short)(u.y >> 16)) +
               sA[d + 4] * bf2f((unsigned short)u.z) +
               sA[d + 5] * bf2f((unsigned short)(u.z >> 16)) +
               sA[d + 6] * bf2f((unsigned short)u.w) +
               sA[d + 7] * bf2f((unsigned short)(u.w >> 16));
      }
    }
    // block-wide mean / var of dot across the 256 outputs
    float s1 = dot, s2 = dot * dot;
#pragma unroll
    for (int off = 32; off > 0; off >>= 1) {
      s1 += __shfl_down(s1, off);
      s2 += __shfl_down(s2, off);
    }
    if (lane == 0) { redS[wv] = s1; redQ[wv] = s2; }
    __syncthreads();
    if (tid == 0) {
      float S = redS[0] + redS[1] + redS[2] + redS[3];
      float Q = redQ[0] + redQ[1] + redQ[2] + redQ[3];
      float mu = S * (1.0f / ADP);
      float var = Q * (1.0f / ADP) - mu * mu;
      sMu = mu;
      sRstd = rsqrtf(var + 1e-5f);
    }
    __syncthreads();
    float y = 0.f;
    if (e >= 0)
      y = (dot - sMu) * sRstd * gamma[e * ADP + tid] + beta[e * ADP + tid];
    anorm[(size_t)t * ADP + tid] = f2bf(y);
  }
}

// ---------------------------------------------------------------------------
extern "C" void kernel_launch(void* const* d_in, const int* in_sizes, int n_in,
                              void* d_out, int out_size, void* d_ws, size_t ws_size,
                              hipStream_t stream) {
  const float* x     = (const float*)d_in[0];
  const float* ew    = (const float*)d_in[1];
  const float* W_up  = (const float*)d_in[2];
  const float* W_ad  = (const float*)d_in[3];
  const float* W_ex  = (const float*)d_in[4];
  const float* gam   = (const float*)d_in[5];
  const float* bet   = (const float*)d_in[6];
  const float* W_pr  = (const float*)d_in[7];
  const float* W_out = (const float*)d_in[8];
  float* out = (float*)d_out;

  // workspace layout (~137 MiB total)
  char* ws = (char*)d_ws;
  size_t off = 0;
  auto alloc = [&](size_t n) {
    char* p = ws + off;
    off += (n + 255) & ~(size_t)255;
    return p;
  };
  unsigned short* xb  = (unsigned short*)alloc((size_t)TOK * DEMB * 2);
  unsigned short* wub = (unsigned short*)alloc((size_t)HID * DEMB * 2);
  unsigned short* wob = (unsigned short*)alloc((size_t)DEMB * HID * 2);
  unsigned short* wab = (unsigned short*)alloc((size_t)ADP * HID * 2);
  unsigned short* web = (unsigned short*)alloc((size_t)NEXP * ADP * ADP * 2);
  unsigned short* wpb = (unsigned short*)alloc((size_t)HID * ADP * 2);
  unsigned short* H   = (unsigned short*)alloc((size_t)TOK * HID * 2);
  float*          P   = (float*)alloc((size_t)4 * TOK * ADP * 4);
  unsigned short* an  = (unsigned short*)alloc((size_t)TOK * ADP * 2);
  int*          route = (int*)alloc((size_t)TOK * 4);

  // 1) bf16 conversion of x + weights
  convert_all<<<9472, 256, 0, stream>>>(x, W_up, W_out, W_ad, W_ex, W_pr,
                                        xb, wub, wob, wab, web, wpb);
  // 2) routing
  route_kernel<<<TOK / 256, 256, 0, stream>>>(ew, route);
  // 3) H = silu(x @ W_up^T)               [8192,4096] K=1024
  gemm128<0><<<dim3(HID / 128, TOK / 128, 1), 256, 0, stream>>>(
      xb, DEMB, wub, DEMB, H, HID, nullptr, DEMB, 0);
  // 4) A = H @ W_adapt^T (split-K=4 partials)  [8192,256] K=4096
  gemm128<1><<<dim3(ADP / 128, TOK / 128, 4), 256, 0, stream>>>(
      H, HID, wab, HID, P, ADP, nullptr, HID / 4, (long)TOK * ADP);
  // 5) per-token expert adapter + LayerNorm -> a_norm bf16
  adapter_ln<<<TOK / 16, 256, 0, stream>>>(P, web, route, gam, bet, an);
  // 6) H += 0.1 * act * (a_norm @ W_proj^T)   (in-place, fuses the combine)
  gemm128<2><<<dim3(HID / 128, TOK / 128, 1), 256, 0, stream>>>(
      an, ADP, wpb, ADP, H, HID, route, ADP, 0);
  // 7) out = H @ W_out^T   (fp32 output; == shared_out + 0.1*combined)
  gemm128<1><<<dim3(DEMB / 128, TOK / 128, 1), 256, 0, stream>>>(
      H, HID, wob, HID, out, DEMB, nullptr, HID, 0);
}

// Round 2
// 513.137 us; speedup vs baseline: 1.0422x; 1.0422x over previous
//
#include <hip/hip_runtime.h>
#include <cstdint>

// Problem constants (fixed by reference: B=4, S=2048)
#define TOK  8192   // B*S
#define DEMB 1024   // N_EMBD
#define HID  4096   // HIDDEN
#define ADP  256    // ADAPT
#define NEXP 8

typedef __bf16 bf16x8 __attribute__((ext_vector_type(8)));
typedef float  f32x4  __attribute__((ext_vector_type(4)));

__device__ __forceinline__ unsigned short f2bf(float f) {
  // round-to-nearest-even fp32 -> bf16 (matches numpy/jax cast for normal values)
  unsigned int u = __float_as_uint(f);
  u += 0x7fffu + ((u >> 16) & 1u);
  return (unsigned short)(u >> 16);
}
__device__ __forceinline__ float bf2f(unsigned short b) {
  return __uint_as_float(((unsigned int)b) << 16);
}

// ---------------------------------------------------------------------------
// fp32 -> bf16 conversion for x and all weight tensors, one kernel.
// Each block converts 2048 contiguous elements (256 thr x 2 x float4).
// ---------------------------------------------------------------------------
__global__ __launch_bounds__(256) void convert_all(
    const float* __restrict__ x, const float* __restrict__ wup,
    const float* __restrict__ wout, const float* __restrict__ wadapt,
    const float* __restrict__ wexp, const float* __restrict__ wproj,
    unsigned short* __restrict__ xb, unsigned short* __restrict__ wub,
    unsigned short* __restrict__ wob, unsigned short* __restrict__ wab,
    unsigned short* __restrict__ web, unsigned short* __restrict__ wpb) {
  int b = blockIdx.x;
  const float* src; unsigned short* dst; int lb;
  if      (b < 4096) { src = x;      dst = xb;  lb = b; }
  else if (b < 6144) { src = wup;    dst = wub; lb = b - 4096; }
  else if (b < 8192) { src = wout;   dst = wob; lb = b - 6144; }
  else if (b < 8704) { src = wadapt; dst = wab; lb = b - 8192; }
  else if (b < 8960) { src = wexp;   dst = web; lb = b - 8704; }
  else               { src = wproj;  dst = wpb; lb = b - 8960; }
  size_t base = (size_t)lb * 2048;
#pragma unroll
  for (int h = 0; h < 2; ++h) {
    size_t off = base + (size_t)h * 1024 + (size_t)threadIdx.x * 4;
    float4 v = *(const float4*)(src + off);
    ushort4 o;
    o.x = f2bf(v.x); o.y = f2bf(v.y); o.z = f2bf(v.z); o.w = f2bf(v.w);
    *(ushort4*)(dst + off) = o;
  }
}

// ---------------------------------------------------------------------------
// Routing: last active expert index per token (-1 if none).
// ---------------------------------------------------------------------------
__global__ __launch_bounds__(256) void route_kernel(const float* __restrict__ ew,
                                                    int* __restrict__ route) {
  int t = blockIdx.x * 256 + threadIdx.x;
  const float* p = ew + (size_t)t * NEXP;
  int r = -1;
#pragma unroll
  for (int e = 0; e < NEXP; ++e)
    if (p[e] > 0.f) r = e;
  route[t] = r;
}

// ---------------------------------------------------------------------------
// 128x128x(BK=64) bf16 MFMA GEMM, C[m,n] = sum_k A[m,k]*B[n,k]  (B^T layout).
// m97 structure: global_load_lds width-16 staging, XOR-swizzled LDS (kills
// ds_read_b128 bank conflicts), 4 waves in 2x2 grid, 4x4 16x16x32 tiles/wave.
// EPI: 0 = silu -> bf16, 1 = fp32 store (+split-K offset), 2 = in-place
//      bf16 C := C + 0.1*act(row)*acc.
// ---------------------------------------------------------------------------
__device__ __forceinline__ void stage_tile(const unsigned short* __restrict__ g,
                                           int ldg, unsigned short* lds,
                                           int wave, int lane) {
  // tile = 128 rows x 64 cols bf16; 16 chunks of 8 rows; wave stages 4 chunks.
  // LDS dst for lane i is base + i*16B (wave-uniform base semantics), i.e.
  // row = chunk*8 + i/8, k-block = i%8. Source column is XOR-swizzled so the
  // LDS image holds (m, kb^ (m&7)) -> conflict-free ds_read_b128 later.
  int srow = lane >> 3;
  int scol = ((lane & 7) ^ (srow & 7)) * 8;
#pragma unroll
  for (int c = 0; c < 4; ++c) {
    int chunk = wave * 4 + c;
    const unsigned short* gp = g + (size_t)(chunk * 8 + srow) * ldg + scol;
    unsigned short* lp = lds + chunk * 512;
    __builtin_amdgcn_global_load_lds(
        (const __attribute__((address_space(1))) unsigned int*)(uintptr_t)gp,
        (__attribute__((address_space(3))) unsigned int*)(uintptr_t)lp,
        16, 0, 0);
  }
}

template <int EPI>
__global__ __launch_bounds__(256) void gemm128(
    const unsigned short* __restrict__ A, int lda,
    const unsigned short* __restrict__ B, int ldb,
    void* __restrict__ C, int ldc,
    const int* __restrict__ route, int kLen, long splitStride) {
  __shared__ unsigned short As[128 * 64];
  __shared__ unsigned short Bs[128 * 64];
  const int lane = threadIdx.x & 63;
  const int wave = threadIdx.x >> 6;
  const int wm = wave >> 1, wn = wave & 1;
  const long rowBase = (long)blockIdx.y * 128;
  const long colBase = (long)blockIdx.x * 128;
  const int ks = blockIdx.z * kLen;
  const unsigned short* Ap = A + rowBase * lda + ks;
  const unsigned short* Bp = B + colBase * ldb + ks;
  f32x4 acc[4][4] = {};

  for (int kt = 0; kt < kLen; kt += 64) {
    stage_tile(Ap + kt, lda, As, wave, lane);
    stage_tile(Bp + kt, ldb, Bs, wave, lane);
    __syncthreads();
#pragma unroll
    for (int kk = 0; kk < 64; kk += 32) {
      const int kb = (kk >> 3) + (lane >> 4);   // k-block 0..7
      const int sw = kb ^ (lane & 7);           // swizzled k-block
      bf16x8 af[4], bfr[4];
#pragma unroll
      for (int mt = 0; mt < 4; ++mt) {
        int m = wm * 64 + mt * 16 + (lane & 15);
        af[mt] = *(const bf16x8*)&As[m * 64 + sw * 8];
      }
#pragma unroll
      for (int nt = 0; nt < 4; ++nt) {
        int n = wn * 64 + nt * 16 + (lane & 15);
        bfr[nt] = *(const bf16x8*)&Bs[n * 64 + sw * 8];
      }
#pragma unroll
      for (int mt = 0; mt < 4; ++mt)
#pragma unroll
        for (int nt = 0; nt < 4; ++nt)
          acc[mt][nt] = __builtin_amdgcn_mfma_f32_16x16x32_bf16(
              af[mt], bfr[nt], acc[mt][nt], 0, 0, 0);
    }
    __syncthreads();
  }

  // Epilogue. C/D layout (m89-verified): col = lane&15, row = (lane>>4)*4 + r.
  const int rsub = (lane >> 4) * 4;
  const int csub = lane & 15;
#pragma unroll
  for (int mt = 0; mt < 4; ++mt) {
#pragma unroll
    for (int nt = 0; nt < 4; ++nt) {
      long col = colBase + wn * 64 + nt * 16 + csub;
#pragma unroll
      for (int r = 0; r < 4; ++r) {
        long row = rowBase + wm * 64 + mt * 16 + rsub + r;
        float v = acc[mt][nt][r];
        if (EPI == 0) {
          float s = __fdividef(v, 1.0f + __expf(-v));  // silu
          ((unsigned short*)C)[row * ldc + col] = f2bf(s);
        } else if (EPI == 1) {
          ((float*)C + splitStride * blockIdx.z)[row * ldc + col] = v;
        } else {
          long idx = row * ldc + col;
          float h = bf2f(((unsigned short*)C)[idx]);
          float sc = (route[row] >= 0) ? 0.1f : 0.0f;
          ((unsigned short*)C)[idx] = f2bf(h + sc * v);
        }
      }
    }
  }
}

// ---------------------------------------------------------------------------
// Per-token expert adapter (256x256 matvec) + LayerNorm.
// ONE token per block (8192 blocks) — kills the old serial 16-token loop that
// made this kernel latency-bound (133 us, 22% occupancy, 28% VALUBusy).
// Thread o computes output element o via 256-MAC dot against LDS-broadcast a.
// 4 rotating accumulators break the FMA dependency chain. W_exp (1 MB bf16)
// stays L2-resident; ~1 GB of L2 reads -> ~31 us floor.
// ---------------------------------------------------------------------------
__global__ __launch_bounds__(256) void adapter_ln(
    const float* __restrict__ P,            // [4][TOK][ADP] fp32 partials
    const unsigned short* __restrict__ Wexp,// [8][256][256] bf16
    const int* __restrict__ route,
    const float* __restrict__ gamma, const float* __restrict__ beta,
    unsigned short* __restrict__ anorm) {
  __shared__ float sA[ADP];
  __shared__ float redS[4], redQ[4];
  __shared__ float sMu, sRstd;
  const int tid = threadIdx.x;
  const int lane = tid & 63, wv = tid >> 6;
  const int t = blockIdx.x;

  // a[tid] = sum of 4 split-K partials (coalesced fp32 loads)
  size_t ti = (size_t)t * ADP + tid;
  float a = P[ti] + P[(size_t)TOK * ADP + ti] + P[2 * (size_t)TOK * ADP + ti] +
            P[3 * (size_t)TOK * ADP + ti];
  sA[tid] = a;
  const int e = route[t];
  __syncthreads();

  float dot = 0.f;
  if (e >= 0) {
    const unsigned short* w = Wexp + ((size_t)e * ADP + tid) * ADP;
    float acc[4] = {0.f, 0.f, 0.f, 0.f};
#pragma unroll
    for (int d = 0; d < ADP; d += 8) {
      uint4 u = *(const uint4*)(w + d);
      float4 a0 = *(const float4*)&sA[d];      // wave-uniform broadcast reads
      float4 a1 = *(const float4*)&sA[d + 4];
      float s = a0.x * bf2f((unsigned short)u.x) +
                a0.y * bf2f((unsigned short)(u.x >> 16)) +
                a0.z * bf2f((unsigned short)u.y) +
                a0.w * bf2f((unsigned short)(u.y >> 16)) +
                a1.x * bf2f((unsigned short)u.z) +
                a1.y * bf2f((unsigned short)(u.z >> 16)) +
                a1.z * bf2f((unsigned short)u.w) +
                a1.w * bf2f((unsigned short)(u.w >> 16));
      acc[(d >> 3) & 3] += s;
    }
    dot = (acc[0] + acc[1]) + (acc[2] + acc[3]);
  }

  // block-wide mean / var of dot across the 256 outputs
  float s1 = dot, s2 = dot * dot;
#pragma unroll
  for (int off = 32; off > 0; off >>= 1) {
    s1 += __shfl_down(s1, off);
    s2 += __shfl_down(s2, off);
  }
  if (lane == 0) { redS[wv] = s1; redQ[wv] = s2; }
  __syncthreads();
  if (tid == 0) {
    float S = redS[0] + redS[1] + redS[2] + redS[3];
    float Q = redQ[0] + redQ[1] + redQ[2] + redQ[3];
    float mu = S * (1.0f / ADP);
    float var = Q * (1.0f / ADP) - mu * mu;
    sMu = mu;
    sRstd = rsqrtf(var + 1e-5f);
  }
  __syncthreads();
  float y = 0.f;
  if (e >= 0)
    y = (dot - sMu) * sRstd * gamma[e * ADP + tid] + beta[e * ADP + tid];
  anorm[(size_t)t * ADP + tid] = f2bf(y);
}

// ---------------------------------------------------------------------------
extern "C" void kernel_launch(void* const* d_in, const int* in_sizes, int n_in,
                              void* d_out, int out_size, void* d_ws, size_t ws_size,
                              hipStream_t stream) {
  const float* x     = (const float*)d_in[0];
  const float* ew    = (const float*)d_in[1];
  const float* W_up  = (const float*)d_in[2];
  const float* W_ad  = (const float*)d_in[3];
  const float* W_ex  = (const float*)d_in[4];
  const float* gam   = (const float*)d_in[5];
  const float* bet   = (const float*)d_in[6];
  const float* W_pr  = (const float*)d_in[7];
  const float* W_out = (const float*)d_in[8];
  float* out = (float*)d_out;

  // workspace layout (~137 MiB total)
  char* ws = (char*)d_ws;
  size_t off = 0;
  auto alloc = [&](size_t n) {
    char* p = ws + off;
    off += (n + 255) & ~(size_t)255;
    return p;
  };
  unsigned short* xb  = (unsigned short*)alloc((size_t)TOK * DEMB * 2);
  unsigned short* wub = (unsigned short*)alloc((size_t)HID * DEMB * 2);
  unsigned short* wob = (unsigned short*)alloc((size_t)DEMB * HID * 2);
  unsigned short* wab = (unsigned short*)alloc((size_t)ADP * HID * 2);
  unsigned short* web = (unsigned short*)alloc((size_t)NEXP * ADP * ADP * 2);
  unsigned short* wpb = (unsigned short*)alloc((size_t)HID * ADP * 2);
  unsigned short* H   = (unsigned short*)alloc((size_t)TOK * HID * 2);
  float*          P   = (float*)alloc((size_t)4 * TOK * ADP * 4);
  unsigned short* an  = (unsigned short*)alloc((size_t)TOK * ADP * 2);
  int*          route = (int*)alloc((size_t)TOK * 4);

  // 1) bf16 conversion of x + weights
  convert_all<<<9472, 256, 0, stream>>>(x, W_up, W_out, W_ad, W_ex, W_pr,
                                        xb, wub, wob, wab, web, wpb);
  // 2) routing
  route_kernel<<<TOK / 256, 256, 0, stream>>>(ew, route);
  // 3) H = silu(x @ W_up^T)               [8192,4096] K=1024
  gemm128<0><<<dim3(HID / 128, TOK / 128, 1), 256, 0, stream>>>(
      xb, DEMB, wub, DEMB, H, HID, nullptr, DEMB, 0);
  // 4) A = H @ W_adapt^T (split-K=4 partials)  [8192,256] K=4096
  gemm128<1><<<dim3(ADP / 128, TOK / 128, 4), 256, 0, stream>>>(
      H, HID, wab, HID, P, ADP, nullptr, HID / 4, (long)TOK * ADP);
  // 5) per-token expert adapter + LayerNorm -> a_norm bf16 (1 token/block)
  adapter_ln<<<TOK, 256, 0, stream>>>(P, web, route, gam, bet, an);
  // 6) H += 0.1 * act * (a_norm @ W_proj^T)   (in-place, fuses the combine)
  gemm128<2><<<dim3(HID / 128, TOK / 128, 1), 256, 0, stream>>>(
      an, ADP, wpb, ADP, H, HID, route, ADP, 0);
  // 7) out = H @ W_out^T   (fp32 output; == shared_out + 0.1*combined)
  gemm128<1><<<dim3(DEMB / 128, TOK / 128, 1), 256, 0, stream>>>(
      H, HID, wob, HID, out, DEMB, nullptr, HID, 0);
}

// Round 3
// 434.902 us; speedup vs baseline: 1.2297x; 1.1799x over previous
//
#include <hip/hip_runtime.h>
#include <cstdint>

// Problem constants (fixed by reference: B=4, S=2048)
#define TOK  8192   // B*S
#define DEMB 1024   // N_EMBD
#define HID  4096   // HIDDEN
#define ADP  256    // ADAPT
#define NEXP 8

typedef __bf16 bf16x8 __attribute__((ext_vector_type(8)));
typedef float  f32x4  __attribute__((ext_vector_type(4)));

__device__ __forceinline__ unsigned short f2bf(float f) {
  // round-to-nearest-even fp32 -> bf16 (matches numpy/jax cast for normal values)
  unsigned int u = __float_as_uint(f);
  u += 0x7fffu + ((u >> 16) & 1u);
  return (unsigned short)(u >> 16);
}
__device__ __forceinline__ float bf2f(unsigned short b) {
  return __uint_as_float(((unsigned int)b) << 16);
}

// ---------------------------------------------------------------------------
// fp32 -> bf16 conversion for x and all weight tensors, one kernel.
// Each block converts 2048 contiguous elements (256 thr x 2 x float4).
// ---------------------------------------------------------------------------
__global__ __launch_bounds__(256) void convert_all(
    const float* __restrict__ x, const float* __restrict__ wup,
    const float* __restrict__ wout, const float* __restrict__ wadapt,
    const float* __restrict__ wexp, const float* __restrict__ wproj,
    unsigned short* __restrict__ xb, unsigned short* __restrict__ wub,
    unsigned short* __restrict__ wob, unsigned short* __restrict__ wab,
    unsigned short* __restrict__ web, unsigned short* __restrict__ wpb) {
  int b = blockIdx.x;
  const float* src; unsigned short* dst; int lb;
  if      (b < 4096) { src = x;      dst = xb;  lb = b; }
  else if (b < 6144) { src = wup;    dst = wub; lb = b - 4096; }
  else if (b < 8192) { src = wout;   dst = wob; lb = b - 6144; }
  else if (b < 8704) { src = wadapt; dst = wab; lb = b - 8192; }
  else if (b < 8960) { src = wexp;   dst = web; lb = b - 8704; }
  else               { src = wproj;  dst = wpb; lb = b - 8960; }
  size_t base = (size_t)lb * 2048;
#pragma unroll
  for (int h = 0; h < 2; ++h) {
    size_t off = base + (size_t)h * 1024 + (size_t)threadIdx.x * 4;
    float4 v = *(const float4*)(src + off);
    ushort4 o;
    o.x = f2bf(v.x); o.y = f2bf(v.y); o.z = f2bf(v.z); o.w = f2bf(v.w);
    *(ushort4*)(dst + off) = o;
  }
}

// ---------------------------------------------------------------------------
// Routing: last active expert index per token (-1 if none).
// ---------------------------------------------------------------------------
__global__ __launch_bounds__(256) void route_kernel(const float* __restrict__ ew,
                                                    int* __restrict__ route) {
  int t = blockIdx.x * 256 + threadIdx.x;
  const float* p = ew + (size_t)t * NEXP;
  int r = -1;
#pragma unroll
  for (int e = 0; e < NEXP; ++e)
    if (p[e] > 0.f) r = e;
  route[t] = r;
}

// ---------------------------------------------------------------------------
// 128x128x(BK=64) bf16 MFMA GEMM, C[m,n] = sum_k A[m,k]*B[n,k]  (B^T layout).
// m97 structure: global_load_lds width-16 staging, XOR-swizzled LDS (kills
// ds_read_b128 bank conflicts), 4 waves in 2x2 grid, 4x4 16x16x32 tiles/wave.
// EPI: 0 = silu -> bf16, 1 = fp32 store (+split-K offset), 2 = in-place
//      bf16 C := C + 0.1*act(row)*acc, 3 = expert-select fp32 store:
//      keep element only if route[row] == col>>8 (cols span 8 experts x 256).
// ---------------------------------------------------------------------------
__device__ __forceinline__ void stage_tile(const unsigned short* __restrict__ g,
                                           int ldg, unsigned short* lds,
                                           int wave, int lane) {
  // tile = 128 rows x 64 cols bf16; 16 chunks of 8 rows; wave stages 4 chunks.
  // LDS dst for lane i is base + i*16B (wave-uniform base semantics), i.e.
  // row = chunk*8 + i/8, k-block = i%8. Source column is XOR-swizzled so the
  // LDS image holds (m, kb^ (m&7)) -> conflict-free ds_read_b128 later.
  int srow = lane >> 3;
  int scol = ((lane & 7) ^ (srow & 7)) * 8;
#pragma unroll
  for (int c = 0; c < 4; ++c) {
    int chunk = wave * 4 + c;
    const unsigned short* gp = g + (size_t)(chunk * 8 + srow) * ldg + scol;
    unsigned short* lp = lds + chunk * 512;
    __builtin_amdgcn_global_load_lds(
        (const __attribute__((address_space(1))) unsigned int*)(uintptr_t)gp,
        (__attribute__((address_space(3))) unsigned int*)(uintptr_t)lp,
        16, 0, 0);
  }
}

template <int EPI>
__global__ __launch_bounds__(256) void gemm128(
    const unsigned short* __restrict__ A, int lda,
    const unsigned short* __restrict__ B, int ldb,
    void* __restrict__ C, int ldc,
    const int* __restrict__ route, int kLen, long splitStride) {
  __shared__ unsigned short As[128 * 64];
  __shared__ unsigned short Bs[128 * 64];
  const int lane = threadIdx.x & 63;
  const int wave = threadIdx.x >> 6;
  const int wm = wave >> 1, wn = wave & 1;
  const long rowBase = (long)blockIdx.y * 128;
  const long colBase = (long)blockIdx.x * 128;
  const int ks = blockIdx.z * kLen;
  const unsigned short* Ap = A + rowBase * lda + ks;
  const unsigned short* Bp = B + colBase * ldb + ks;
  f32x4 acc[4][4] = {};

  for (int kt = 0; kt < kLen; kt += 64) {
    stage_tile(Ap + kt, lda, As, wave, lane);
    stage_tile(Bp + kt, ldb, Bs, wave, lane);
    __syncthreads();
#pragma unroll
    for (int kk = 0; kk < 64; kk += 32) {
      const int kb = (kk >> 3) + (lane >> 4);   // k-block 0..7
      const int sw = kb ^ (lane & 7);           // swizzled k-block
      bf16x8 af[4], bfr[4];
#pragma unroll
      for (int mt = 0; mt < 4; ++mt) {
        int m = wm * 64 + mt * 16 + (lane & 15);
        af[mt] = *(const bf16x8*)&As[m * 64 + sw * 8];
      }
#pragma unroll
      for (int nt = 0; nt < 4; ++nt) {
        int n = wn * 64 + nt * 16 + (lane & 15);
        bfr[nt] = *(const bf16x8*)&Bs[n * 64 + sw * 8];
      }
#pragma unroll
      for (int mt = 0; mt < 4; ++mt)
#pragma unroll
        for (int nt = 0; nt < 4; ++nt)
          acc[mt][nt] = __builtin_amdgcn_mfma_f32_16x16x32_bf16(
              af[mt], bfr[nt], acc[mt][nt], 0, 0, 0);
    }
    __syncthreads();
  }

  // Epilogue. C/D layout (m89-verified): col = lane&15, row = (lane>>4)*4 + r.
  const int rsub = (lane >> 4) * 4;
  const int csub = lane & 15;
#pragma unroll
  for (int mt = 0; mt < 4; ++mt) {
#pragma unroll
    for (int nt = 0; nt < 4; ++nt) {
      long col = colBase + wn * 64 + nt * 16 + csub;
#pragma unroll
      for (int r = 0; r < 4; ++r) {
        long row = rowBase + wm * 64 + mt * 16 + rsub + r;
        float v = acc[mt][nt][r];
        if (EPI == 0) {
          float s = __fdividef(v, 1.0f + __expf(-v));  // silu
          ((unsigned short*)C)[row * ldc + col] = f2bf(s);
        } else if (EPI == 1) {
          ((float*)C + splitStride * blockIdx.z)[row * ldc + col] = v;
        } else if (EPI == 2) {
          long idx = row * ldc + col;
          float h = bf2f(((unsigned short*)C)[idx]);
          float sc = (route[row] >= 0) ? 0.1f : 0.0f;
          ((unsigned short*)C)[idx] = f2bf(h + sc * v);
        } else {  // EPI == 3: expert-select store into a_sel [TOK][ADP] fp32
          if (route[row] == (int)(col >> 8))
            ((float*)C)[row * ADP + (col & 255)] = v;
        }
      }
    }
  }
}

// ---------------------------------------------------------------------------
// Sum the 4 split-K fp32 partials of A and cast to bf16 (feeds expert GEMM).
// Each thread handles 4 consecutive elements; fully coalesced float4 loads.
// ---------------------------------------------------------------------------
__global__ __launch_bounds__(256) void reduce_cast(
    const float* __restrict__ P, unsigned short* __restrict__ ab) {
  size_t i = ((size_t)blockIdx.x * 256 + threadIdx.x) * 4;
  const size_t stride = (size_t)TOK * ADP;
  float4 p0 = *(const float4*)(P + i);
  float4 p1 = *(const float4*)(P + stride + i);
  float4 p2 = *(const float4*)(P + 2 * stride + i);
  float4 p3 = *(const float4*)(P + 3 * stride + i);
  ushort4 o;
  o.x = f2bf(p0.x + p1.x + p2.x + p3.x);
  o.y = f2bf(p0.y + p1.y + p2.y + p3.y);
  o.z = f2bf(p0.z + p1.z + p2.z + p3.z);
  o.w = f2bf(p0.w + p1.w + p2.w + p3.w);
  *(ushort4*)(ab + i) = o;
}

// ---------------------------------------------------------------------------
// LayerNorm over a_sel rows: one WAVE per token (4 tokens / 256-thread block).
// Lane l holds 4 consecutive elements (float4); wave-shuffle reduction; no
// __syncthreads. Writes bf16 a_norm (0 for inactive tokens).
// ---------------------------------------------------------------------------
__global__ __launch_bounds__(256) void ln_kernel(
    const float* __restrict__ asel, const int* __restrict__ route,
    const float* __restrict__ gamma, const float* __restrict__ beta,
    unsigned short* __restrict__ anorm) {
  const int lane = threadIdx.x & 63;
  const int t = blockIdx.x * 4 + (threadIdx.x >> 6);
  const int e = route[t];
  float4 v = *(const float4*)(asel + (size_t)t * ADP + lane * 4);
  float s1 = v.x + v.y + v.z + v.w;
  float s2 = v.x * v.x + v.y * v.y + v.z * v.z + v.w * v.w;
#pragma unroll
  for (int off = 32; off > 0; off >>= 1) {
    s1 += __shfl_down(s1, off);
    s2 += __shfl_down(s2, off);
  }
  s1 = __shfl(s1, 0);
  s2 = __shfl(s2, 0);
  float mu = s1 * (1.0f / ADP);
  float var = s2 * (1.0f / ADP) - mu * mu;
  float rstd = rsqrtf(var + 1e-5f);
  ushort4 o;
  if (e >= 0) {
    float4 g = *(const float4*)(gamma + (size_t)e * ADP + lane * 4);
    float4 b = *(const float4*)(beta + (size_t)e * ADP + lane * 4);
    o.x = f2bf((v.x - mu) * rstd * g.x + b.x);
    o.y = f2bf((v.y - mu) * rstd * g.y + b.y);
    o.z = f2bf((v.z - mu) * rstd * g.z + b.z);
    o.w = f2bf((v.w - mu) * rstd * g.w + b.w);
  } else {
    o.x = o.y = o.z = o.w = 0;
  }
  *(ushort4*)(anorm + (size_t)t * ADP + lane * 4) = o;
}

// ---------------------------------------------------------------------------
extern "C" void kernel_launch(void* const* d_in, const int* in_sizes, int n_in,
                              void* d_out, int out_size, void* d_ws, size_t ws_size,
                              hipStream_t stream) {
  const float* x     = (const float*)d_in[0];
  const float* ew    = (const float*)d_in[1];
  const float* W_up  = (const float*)d_in[2];
  const float* W_ad  = (const float*)d_in[3];
  const float* W_ex  = (const float*)d_in[4];
  const float* gam   = (const float*)d_in[5];
  const float* bet   = (const float*)d_in[6];
  const float* W_pr  = (const float*)d_in[7];
  const float* W_out = (const float*)d_in[8];
  float* out = (float*)d_out;

  // workspace layout (~148 MiB total)
  char* ws = (char*)d_ws;
  size_t off = 0;
  auto alloc = [&](size_t n) {
    char* p = ws + off;
    off += (n + 255) & ~(size_t)255;
    return p;
  };
  unsigned short* xb  = (unsigned short*)alloc((size_t)TOK * DEMB * 2);
  unsigned short* wub = (unsigned short*)alloc((size_t)HID * DEMB * 2);
  unsigned short* wob = (unsigned short*)alloc((size_t)DEMB * HID * 2);
  unsigned short* wab = (unsigned short*)alloc((size_t)ADP * HID * 2);
  unsigned short* web = (unsigned short*)alloc((size_t)NEXP * ADP * ADP * 2);
  unsigned short* wpb = (unsigned short*)alloc((size_t)HID * ADP * 2);
  unsigned short* H   = (unsigned short*)alloc((size_t)TOK * HID * 2);
  float*          P   = (float*)alloc((size_t)4 * TOK * ADP * 4);
  unsigned short* ab  = (unsigned short*)alloc((size_t)TOK * ADP * 2);
  unsigned short* an  = (unsigned short*)alloc((size_t)TOK * ADP * 2);
  int*          route = (int*)alloc((size_t)TOK * 4);
  // a_sel aliases P: P is fully consumed by reduce_cast before gemm128<3>
  // writes a_sel (no intra-kernel overlap).
  float* asel = P;

  // 1) bf16 conversion of x + weights
  convert_all<<<9472, 256, 0, stream>>>(x, W_up, W_out, W_ad, W_ex, W_pr,
                                        xb, wub, wob, wab, web, wpb);
  // 2) routing
  route_kernel<<<TOK / 256, 256, 0, stream>>>(ew, route);
  // 3) H = silu(x @ W_up^T)               [8192,4096] K=1024
  gemm128<0><<<dim3(HID / 128, TOK / 128, 1), 256, 0, stream>>>(
      xb, DEMB, wub, DEMB, H, HID, nullptr, DEMB, 0);
  // 4) A = H @ W_adapt^T (split-K=4 partials)  [8192,256] K=4096
  gemm128<1><<<dim3(ADP / 128, TOK / 128, 4), 256, 0, stream>>>(
      H, HID, wab, HID, P, ADP, nullptr, HID / 4, (long)TOK * ADP);
  // 5a) a = sum partials -> bf16
  reduce_cast<<<TOK * ADP / 1024, 256, 0, stream>>>(P, ab);
  // 5b) a_all = a @ W_all^T for all 8 experts; keep winning slice -> a_sel
  //     [8192, 2048] K=256 via MFMA (replaces the L1-bound VALU matvec)
  gemm128<3><<<dim3(NEXP * ADP / 128, TOK / 128, 1), 256, 0, stream>>>(
      ab, ADP, web, ADP, asel, ADP, route, ADP, 0);
  // 5c) LayerNorm per token -> a_norm bf16 (one wave per token)
  ln_kernel<<<TOK / 4, 256, 0, stream>>>(asel, route, gam, bet, an);
  // 6) H += 0.1 * act * (a_norm @ W_proj^T)   (in-place, fuses the combine)
  gemm128<2><<<dim3(HID / 128, TOK / 128, 1), 256, 0, stream>>>(
      an, ADP, wpb, ADP, H, HID, route, ADP, 0);
  // 7) out = H @ W_out^T   (fp32 output; == shared_out + 0.1*combined)
  gemm128<1><<<dim3(DEMB / 128, TOK / 128, 1), 256, 0, stream>>>(
      H, HID, wob, HID, out, DEMB, nullptr, HID, 0);
}

// Round 4
// 399.632 us; speedup vs baseline: 1.3382x; 1.0883x over previous
//
#include <hip/hip_runtime.h>
#include <cstdint>

// Problem constants (fixed by reference: B=4, S=2048)
#define TOK  8192   // B*S
#define DEMB 1024   // N_EMBD
#define HID  4096   // HIDDEN
#define ADP  256    // ADAPT
#define NEXP 8
#define KAUG 4352   // HID + ADP (K-augmented out-proj)

typedef __bf16 bf16x8 __attribute__((ext_vector_type(8)));
typedef float  f32x4  __attribute__((ext_vector_type(4)));

__device__ __forceinline__ unsigned short f2bf(float f) {
  // round-to-nearest-even fp32 -> bf16 (matches numpy/jax cast for normal values)
  unsigned int u = __float_as_uint(f);
  u += 0x7fffu + ((u >> 16) & 1u);
  return (unsigned short)(u >> 16);
}
__device__ __forceinline__ float bf2f(unsigned short b) {
  return __uint_as_float(((unsigned int)b) << 16);
}

// ---------------------------------------------------------------------------
// fp32 -> bf16 conversion for x and weights + routing, one kernel.
// Each block converts 2048 contiguous elements (256 thr x 2 x float4).
// W_out is written with row stride KAUG (leaving tail cols for Wcomb).
// Blocks 8960..8991 compute routing (last active expert, -1 if none).
// ---------------------------------------------------------------------------
__global__ __launch_bounds__(256) void convert_all(
    const float* __restrict__ x, const float* __restrict__ wup,
    const float* __restrict__ wout, const float* __restrict__ wadapt,
    const float* __restrict__ wexp, const float* __restrict__ ew,
    unsigned short* __restrict__ xb, unsigned short* __restrict__ wub,
    unsigned short* __restrict__ wob, unsigned short* __restrict__ wab,
    unsigned short* __restrict__ web, int* __restrict__ route) {
  int b = blockIdx.x;
  if (b >= 8960) {  // routing
    int t = (b - 8960) * 256 + threadIdx.x;
    const float* p = ew + (size_t)t * NEXP;
    int r = -1;
#pragma unroll
    for (int e = 0; e < NEXP; ++e)
      if (p[e] > 0.f) r = e;
    route[t] = r;
    return;
  }
  const float* src; unsigned short* dst; int lb; bool strided = false;
  if      (b < 4096) { src = x;      dst = xb;  lb = b; }
  else if (b < 6144) { src = wup;    dst = wub; lb = b - 4096; }
  else if (b < 8192) { src = wout;   dst = wob; lb = b - 6144; strided = true; }
  else if (b < 8704) { src = wadapt; dst = wab; lb = b - 8192; }
  else               { src = wexp;   dst = web; lb = b - 8704; }
  size_t base = (size_t)lb * 2048;
#pragma unroll
  for (int h = 0; h < 2; ++h) {
    size_t off = base + (size_t)h * 1024 + (size_t)threadIdx.x * 4;
    float4 v = *(const float4*)(src + off);
    ushort4 o;
    o.x = f2bf(v.x); o.y = f2bf(v.y); o.z = f2bf(v.z); o.w = f2bf(v.w);
    size_t doff = strided ? (off >> 12) * KAUG + (off & 4095) : off;
    *(ushort4*)(dst + doff) = o;
  }
}

// ---------------------------------------------------------------------------
// Transpose-convert W_proj [4096,256] fp32 -> wpT [256,4096] bf16.
// 64x64 LDS tiles, padded stride 65 (2-way conflicts only = free).
// ---------------------------------------------------------------------------
__global__ __launch_bounds__(256) void wp_transpose(
    const float* __restrict__ wp, unsigned short* __restrict__ wpT) {
  __shared__ float tile[64][65];
  const int h0 = blockIdx.x * 64;  // over 4096
  const int a0 = blockIdx.y * 64;  // over 256
  const int t = threadIdx.x;
  const int r = t >> 4;            // 0..15
  const int c = (t & 15) * 4;      // 0..60
#pragma unroll
  for (int p = 0; p < 4; ++p) {
    int row = p * 16 + r;
    float4 v = *(const float4*)(wp + (size_t)(h0 + row) * ADP + a0 + c);
    tile[c + 0][row] = v.x;
    tile[c + 1][row] = v.y;
    tile[c + 2][row] = v.z;
    tile[c + 3][row] = v.w;
  }
  __syncthreads();
#pragma unroll
  for (int q = 0; q < 2; ++q) {
    int idx = q * 256 + t;
    int al = idx >> 3;             // a local 0..63
    int hg = (idx & 7) * 8;        // h local 0,8,..,56
    unsigned int w0 = (unsigned int)f2bf(tile[al][hg + 0]) |
                      ((unsigned int)f2bf(tile[al][hg + 1]) << 16);
    unsigned int w1 = (unsigned int)f2bf(tile[al][hg + 2]) |
                      ((unsigned int)f2bf(tile[al][hg + 3]) << 16);
    unsigned int w2 = (unsigned int)f2bf(tile[al][hg + 4]) |
                      ((unsigned int)f2bf(tile[al][hg + 5]) << 16);
    unsigned int w3 = (unsigned int)f2bf(tile[al][hg + 6]) |
                      ((unsigned int)f2bf(tile[al][hg + 7]) << 16);
    uint4 o = make_uint4(w0, w1, w2, w3);
    *(uint4*)(wpT + (size_t)(a0 + al) * HID + h0 + hg) = o;
  }
}

// ---------------------------------------------------------------------------
// 128x128x(BK=64) bf16 MFMA GEMM, C[m,n] = sum_k A[m,k]*B[n,k]  (B^T layout).
// m97 structure: global_load_lds width-16 staging, XOR-swizzled LDS (kills
// ds_read_b128 bank conflicts), 4 waves in 2x2 grid, 4x4 16x16x32 tiles/wave.
// EPI: 0 = silu -> bf16, 1 = fp32 store (+split-K offset),
//      3 = expert-select fp32 store (keep iff route[row] == col>>8).
// ---------------------------------------------------------------------------
__device__ __forceinline__ void stage_tile(const unsigned short* __restrict__ g,
                                           int ldg, unsigned short* lds,
                                           int wave, int lane) {
  // tile = 128 rows x 64 cols bf16; 16 chunks of 8 rows; wave stages 4 chunks.
  // LDS dst for lane i is base + i*16B (wave-uniform base semantics), i.e.
  // row = chunk*8 + i/8, k-block = i%8. Source column is XOR-swizzled so the
  // LDS image holds (m, kb^ (m&7)) -> conflict-free ds_read_b128 later.
  int srow = lane >> 3;
  int scol = ((lane & 7) ^ (srow & 7)) * 8;
#pragma unroll
  for (int c = 0; c < 4; ++c) {
    int chunk = wave * 4 + c;
    const unsigned short* gp = g + (size_t)(chunk * 8 + srow) * ldg + scol;
    unsigned short* lp = lds + chunk * 512;
    __builtin_amdgcn_global_load_lds(
        (const __attribute__((address_space(1))) unsigned int*)(uintptr_t)gp,
        (__attribute__((address_space(3))) unsigned int*)(uintptr_t)lp,
        16, 0, 0);
  }
}

template <int EPI>
__global__ __launch_bounds__(256) void gemm128(
    const unsigned short* __restrict__ A, int lda,
    const unsigned short* __restrict__ B, int ldb,
    void* __restrict__ C, int ldc,
    const int* __restrict__ route, int kLen, long splitStride) {
  __shared__ unsigned short As[128 * 64];
  __shared__ unsigned short Bs[128 * 64];
  const int lane = threadIdx.x & 63;
  const int wave = threadIdx.x >> 6;
  const int wm = wave >> 1, wn = wave & 1;
  const long rowBase = (long)blockIdx.y * 128;
  const long colBase = (long)blockIdx.x * 128;
  const int ks = blockIdx.z * kLen;
  const unsigned short* Ap = A + rowBase * lda + ks;
  const unsigned short* Bp = B + colBase * ldb + ks;
  f32x4 acc[4][4] = {};

  for (int kt = 0; kt < kLen; kt += 64) {
    stage_tile(Ap + kt, lda, As, wave, lane);
    stage_tile(Bp + kt, ldb, Bs, wave, lane);
    __syncthreads();
#pragma unroll
    for (int kk = 0; kk < 64; kk += 32) {
      const int kb = (kk >> 3) + (lane >> 4);   // k-block 0..7
      const int sw = kb ^ (lane & 7);           // swizzled k-block
      bf16x8 af[4], bfr[4];
#pragma unroll
      for (int mt = 0; mt < 4; ++mt) {
        int m = wm * 64 + mt * 16 + (lane & 15);
        af[mt] = *(const bf16x8*)&As[m * 64 + sw * 8];
      }
#pragma unroll
      for (int nt = 0; nt < 4; ++nt) {
        int n = wn * 64 + nt * 16 + (lane & 15);
        bfr[nt] = *(const bf16x8*)&Bs[n * 64 + sw * 8];
      }
#pragma unroll
      for (int mt = 0; mt < 4; ++mt)
#pragma unroll
        for (int nt = 0; nt < 4; ++nt)
          acc[mt][nt] = __builtin_amdgcn_mfma_f32_16x16x32_bf16(
              af[mt], bfr[nt], acc[mt][nt], 0, 0, 0);
    }
    __syncthreads();
  }

  // Epilogue. C/D layout (m89-verified): col = lane&15, row = (lane>>4)*4 + r.
  const int rsub = (lane >> 4) * 4;
  const int csub = lane & 15;
#pragma unroll
  for (int mt = 0; mt < 4; ++mt) {
#pragma unroll
    for (int nt = 0; nt < 4; ++nt) {
      long col = colBase + wn * 64 + nt * 16 + csub;
#pragma unroll
      for (int r = 0; r < 4; ++r) {
        long row = rowBase + wm * 64 + mt * 16 + rsub + r;
        float v = acc[mt][nt][r];
        if (EPI == 0) {
          float s = __fdividef(v, 1.0f + __expf(-v));  // silu
          ((unsigned short*)C)[row * ldc + col] = f2bf(s);
        } else if (EPI == 1) {
          ((float*)C + splitStride * blockIdx.z)[row * ldc + col] = v;
        } else {  // EPI == 3: expert-select store into a_sel [TOK][ADP] fp32
          if (route[row] == (int)(col >> 8))
            ((float*)C)[row * ADP + (col & 255)] = v;
        }
      }
    }
  }
}

// ---------------------------------------------------------------------------
// Sum the 4 split-K fp32 partials of A and cast to bf16 (feeds expert GEMM).
// ---------------------------------------------------------------------------
__global__ __launch_bounds__(256) void reduce_cast(
    const float* __restrict__ P, unsigned short* __restrict__ ab) {
  size_t i = ((size_t)blockIdx.x * 256 + threadIdx.x) * 4;
  const size_t stride = (size_t)TOK * ADP;
  float4 p0 = *(const float4*)(P + i);
  float4 p1 = *(const float4*)(P + stride + i);
  float4 p2 = *(const float4*)(P + 2 * stride + i);
  float4 p3 = *(const float4*)(P + 3 * stride + i);
  ushort4 o;
  o.x = f2bf(p0.x + p1.x + p2.x + p3.x);
  o.y = f2bf(p0.y + p1.y + p2.y + p3.y);
  o.z = f2bf(p0.z + p1.z + p2.z + p3.z);
  o.w = f2bf(p0.w + p1.w + p2.w + p3.w);
  *(ushort4*)(ab + i) = o;
}

// ---------------------------------------------------------------------------
// Sum the 8 split-K fp32 partials of Wcomb = W_out @ W_proj, scale by 0.1,
// cast bf16, and write into the tail columns [4096..4351] of wob_aug.
// ---------------------------------------------------------------------------
__global__ __launch_bounds__(256) void wcomb_reduce(
    const float* __restrict__ Pw, unsigned short* __restrict__ wob) {
  size_t i = ((size_t)blockIdx.x * 256 + threadIdx.x) * 4;  // over 1024*256
  const size_t stride = (size_t)DEMB * ADP;
  float4 s = *(const float4*)(Pw + i);
#pragma unroll
  for (int k = 1; k < 8; ++k) {
    float4 p = *(const float4*)(Pw + k * stride + i);
    s.x += p.x; s.y += p.y; s.z += p.z; s.w += p.w;
  }
  size_t d = i >> 8, a = i & 255;
  ushort4 o;
  o.x = f2bf(0.1f * s.x); o.y = f2bf(0.1f * s.y);
  o.z = f2bf(0.1f * s.z); o.w = f2bf(0.1f * s.w);
  *(ushort4*)(wob + d * KAUG + HID + a) = o;
}

// ---------------------------------------------------------------------------
// LayerNorm over a_sel rows: one WAVE per token (4 tokens / 256-thread block).
// Writes bf16 a_norm into the tail columns [4096..4351] of H_aug (0 for
// inactive tokens); the 0.1 combine scale is folded into Wcomb.
// ---------------------------------------------------------------------------
__global__ __launch_bounds__(256) void ln_kernel(
    const float* __restrict__ asel, const int* __restrict__ route,
    const float* __restrict__ gamma, const float* __restrict__ beta,
    unsigned short* __restrict__ haug) {
  const int lane = threadIdx.x & 63;
  const int t = blockIdx.x * 4 + (threadIdx.x >> 6);
  const int e = route[t];
  float4 v = *(const float4*)(asel + (size_t)t * ADP + lane * 4);
  float s1 = v.x + v.y + v.z + v.w;
  float s2 = v.x * v.x + v.y * v.y + v.z * v.z + v.w * v.w;
#pragma unroll
  for (int off = 32; off > 0; off >>= 1) {
    s1 += __shfl_down(s1, off);
    s2 += __shfl_down(s2, off);
  }
  s1 = __shfl(s1, 0);
  s2 = __shfl(s2, 0);
  float mu = s1 * (1.0f / ADP);
  float var = s2 * (1.0f / ADP) - mu * mu;
  float rstd = rsqrtf(var + 1e-5f);
  ushort4 o;
  if (e >= 0) {
    float4 g = *(const float4*)(gamma + (size_t)e * ADP + lane * 4);
    float4 b = *(const float4*)(beta + (size_t)e * ADP + lane * 4);
    o.x = f2bf((v.x - mu) * rstd * g.x + b.x);
    o.y = f2bf((v.y - mu) * rstd * g.y + b.y);
    o.z = f2bf((v.z - mu) * rstd * g.z + b.z);
    o.w = f2bf((v.w - mu) * rstd * g.w + b.w);
  } else {
    o.x = o.y = o.z = o.w = 0;
  }
  *(ushort4*)(haug + (size_t)t * KAUG + HID + lane * 4) = o;
}

// ---------------------------------------------------------------------------
extern "C" void kernel_launch(void* const* d_in, const int* in_sizes, int n_in,
                              void* d_out, int out_size, void* d_ws, size_t ws_size,
                              hipStream_t stream) {
  const float* x     = (const float*)d_in[0];
  const float* ew    = (const float*)d_in[1];
  const float* W_up  = (const float*)d_in[2];
  const float* W_ad  = (const float*)d_in[3];
  const float* W_ex  = (const float*)d_in[4];
  const float* gam   = (const float*)d_in[5];
  const float* bet   = (const float*)d_in[6];
  const float* W_pr  = (const float*)d_in[7];
  const float* W_out = (const float*)d_in[8];
  float* out = (float*)d_out;

  // workspace layout (~150 MiB total)
  char* ws = (char*)d_ws;
  size_t off = 0;
  auto alloc = [&](size_t n) {
    char* p = ws + off;
    off += (n + 255) & ~(size_t)255;
    return p;
  };
  unsigned short* xb   = (unsigned short*)alloc((size_t)TOK * DEMB * 2);
  unsigned short* wub  = (unsigned short*)alloc((size_t)HID * DEMB * 2);
  unsigned short* wob  = (unsigned short*)alloc((size_t)DEMB * KAUG * 2);  // [Wout | Wcomb]
  unsigned short* wab  = (unsigned short*)alloc((size_t)ADP * HID * 2);
  unsigned short* web  = (unsigned short*)alloc((size_t)NEXP * ADP * ADP * 2);
  unsigned short* wpT  = (unsigned short*)alloc((size_t)ADP * HID * 2);    // Wproj^T bf16
  unsigned short* Haug = (unsigned short*)alloc((size_t)TOK * KAUG * 2);   // [H | anorm]
  float*          P    = (float*)alloc((size_t)4 * TOK * ADP * 4);
  float*          Pw   = (float*)alloc((size_t)8 * DEMB * ADP * 4);
  unsigned short* ab   = (unsigned short*)alloc((size_t)TOK * ADP * 2);
  int*          route  = (int*)alloc((size_t)TOK * 4);
  // a_sel aliases P: P fully consumed by reduce_cast before gemm128<3> writes.
  float* asel = P;

  // 1) bf16 conversion of x + weights (wout strided into wob_aug) + routing
  convert_all<<<8992, 256, 0, stream>>>(x, W_up, W_out, W_ad, W_ex, ew,
                                        xb, wub, wob, wab, web, route);
  // 1b) Wproj^T bf16
  wp_transpose<<<dim3(HID / 64, ADP / 64), 256, 0, stream>>>(W_pr, wpT);
  // 1c) Wcomb = W_out @ W_proj (split-K=8 fp32 partials) -> 0.1x bf16 tail of wob
  gemm128<1><<<dim3(ADP / 128, DEMB / 128, 8), 256, 0, stream>>>(
      wob, KAUG, wpT, HID, Pw, ADP, nullptr, HID / 8, (long)DEMB * ADP);
  wcomb_reduce<<<DEMB * ADP / 1024, 256, 0, stream>>>(Pw, wob);
  // 3) H = silu(x @ W_up^T) into cols [0,4096) of H_aug
  gemm128<0><<<dim3(HID / 128, TOK / 128, 1), 256, 0, stream>>>(
      xb, DEMB, wub, DEMB, Haug, KAUG, nullptr, DEMB, 0);
  // 4) A = H @ W_adapt^T (split-K=4 partials)  [8192,256] K=4096
  gemm128<1><<<dim3(ADP / 128, TOK / 128, 4), 256, 0, stream>>>(
      Haug, KAUG, wab, HID, P, ADP, nullptr, HID / 4, (long)TOK * ADP);
  // 5a) a = sum partials -> bf16
  reduce_cast<<<TOK * ADP / 1024, 256, 0, stream>>>(P, ab);
  // 5b) a_all = a @ W_all^T for all 8 experts; keep winning slice -> a_sel
  gemm128<3><<<dim3(NEXP * ADP / 128, TOK / 128, 1), 256, 0, stream>>>(
      ab, ADP, web, ADP, asel, ADP, route, ADP, 0);
  // 5c) LayerNorm per token -> bf16 into tail cols of H_aug
  ln_kernel<<<TOK / 4, 256, 0, stream>>>(asel, route, gam, bet, Haug);
  // 7) out = H_aug @ [Wout | Wcomb]^T, K=4352
  //    == shared_out + 0.1*combined (gemm<2> eliminated by K-augmentation)
  gemm128<1><<<dim3(DEMB / 128, TOK / 128, 1), 256, 0, stream>>>(
      Haug, KAUG, wob, KAUG, out, DEMB, nullptr, KAUG, 0);
}

// Round 5
// 375.707 us; speedup vs baseline: 1.4235x; 1.0637x over previous
//
#include <hip/hip_runtime.h>
#include <cstdint>

// Problem constants (fixed by reference: B=4, S=2048)
#define TOK  8192   // B*S
#define DEMB 1024   // N_EMBD
#define HID  4096   // HIDDEN
#define ADP  256    // ADAPT
#define NEXP 8
#define KAUG 4352   // HID + ADP (K-augmented out-proj)

typedef __bf16 bf16x8 __attribute__((ext_vector_type(8)));
typedef float  f32x4  __attribute__((ext_vector_type(4)));

__device__ __forceinline__ unsigned short f2bf(float f) {
  // round-to-nearest-even fp32 -> bf16 (matches numpy/jax cast for normal values)
  unsigned int u = __float_as_uint(f);
  u += 0x7fffu + ((u >> 16) & 1u);
  return (unsigned short)(u >> 16);
}
__device__ __forceinline__ float bf2f(unsigned short b) {
  return __uint_as_float(((unsigned int)b) << 16);
}

// ---------------------------------------------------------------------------
// fp32 -> bf16 conversion for x and weights + routing, one kernel.
// Each block converts 2048 contiguous elements (256 thr x 2 x float4).
// W_out is written with row stride KAUG (leaving tail cols for Wcomb).
// Blocks 8960..8991 compute routing (last active expert, -1 if none).
// ---------------------------------------------------------------------------
__global__ __launch_bounds__(256) void convert_all(
    const float* __restrict__ x, const float* __restrict__ wup,
    const float* __restrict__ wout, const float* __restrict__ wadapt,
    const float* __restrict__ wexp, const float* __restrict__ ew,
    unsigned short* __restrict__ xb, unsigned short* __restrict__ wub,
    unsigned short* __restrict__ wob, unsigned short* __restrict__ wab,
    unsigned short* __restrict__ web, int* __restrict__ route) {
  int b = blockIdx.x;
  if (b >= 8960) {  // routing
    int t = (b - 8960) * 256 + threadIdx.x;
    const float* p = ew + (size_t)t * NEXP;
    int r = -1;
#pragma unroll
    for (int e = 0; e < NEXP; ++e)
      if (p[e] > 0.f) r = e;
    route[t] = r;
    return;
  }
  const float* src; unsigned short* dst; int lb; bool strided = false;
  if      (b < 4096) { src = x;      dst = xb;  lb = b; }
  else if (b < 6144) { src = wup;    dst = wub; lb = b - 4096; }
  else if (b < 8192) { src = wout;   dst = wob; lb = b - 6144; strided = true; }
  else if (b < 8704) { src = wadapt; dst = wab; lb = b - 8192; }
  else               { src = wexp;   dst = web; lb = b - 8704; }
  size_t base = (size_t)lb * 2048;
#pragma unroll
  for (int h = 0; h < 2; ++h) {
    size_t off = base + (size_t)h * 1024 + (size_t)threadIdx.x * 4;
    float4 v = *(const float4*)(src + off);
    ushort4 o;
    o.x = f2bf(v.x); o.y = f2bf(v.y); o.z = f2bf(v.z); o.w = f2bf(v.w);
    size_t doff = strided ? (off >> 12) * KAUG + (off & 4095) : off;
    *(ushort4*)(dst + doff) = o;
  }
}

// ---------------------------------------------------------------------------
// Transpose-convert W_proj [4096,256] fp32 -> wpT [256,4096] bf16.
// 64x64 LDS tiles, padded stride 65 (2-way conflicts only = free).
// ---------------------------------------------------------------------------
__global__ __launch_bounds__(256) void wp_transpose(
    const float* __restrict__ wp, unsigned short* __restrict__ wpT) {
  __shared__ float tile[64][65];
  const int h0 = blockIdx.x * 64;  // over 4096
  const int a0 = blockIdx.y * 64;  // over 256
  const int t = threadIdx.x;
  const int r = t >> 4;            // 0..15
  const int c = (t & 15) * 4;      // 0..60
#pragma unroll
  for (int p = 0; p < 4; ++p) {
    int row = p * 16 + r;
    float4 v = *(const float4*)(wp + (size_t)(h0 + row) * ADP + a0 + c);
    tile[c + 0][row] = v.x;
    tile[c + 1][row] = v.y;
    tile[c + 2][row] = v.z;
    tile[c + 3][row] = v.w;
  }
  __syncthreads();
#pragma unroll
  for (int q = 0; q < 2; ++q) {
    int idx = q * 256 + t;
    int al = idx >> 3;             // a local 0..63
    int hg = (idx & 7) * 8;        // h local 0,8,..,56
    unsigned int w0 = (unsigned int)f2bf(tile[al][hg + 0]) |
                      ((unsigned int)f2bf(tile[al][hg + 1]) << 16);
    unsigned int w1 = (unsigned int)f2bf(tile[al][hg + 2]) |
                      ((unsigned int)f2bf(tile[al][hg + 3]) << 16);
    unsigned int w2 = (unsigned int)f2bf(tile[al][hg + 4]) |
                      ((unsigned int)f2bf(tile[al][hg + 5]) << 16);
    unsigned int w3 = (unsigned int)f2bf(tile[al][hg + 6]) |
                      ((unsigned int)f2bf(tile[al][hg + 7]) << 16);
    uint4 o = make_uint4(w0, w1, w2, w3);
    *(uint4*)(wpT + (size_t)(a0 + al) * HID + h0 + hg) = o;
  }
}

// ---------------------------------------------------------------------------
// 128x128x(BK=64) bf16 MFMA GEMM, C[m,n] = sum_k A[m,k]*B[n,k]  (B^T layout).
// m97 structure: global_load_lds width-16 staging, XOR-swizzled LDS (kills
// ds_read_b128 bank conflicts), 4 waves in 2x2 grid, 4x4 16x16x32 tiles/wave.
// XCD-aware block remap: dispatch round-robins linear block id across the 8
// XCDs, so the raw mapping puts one N-strip per XCD and streams ALL of A
// through every XCD (283 MB fetch on the out-proj vs 77 ideal). Remap gives
// each XCD a contiguous band of gy/8 row-tiles with all col-tiles co-resident
// -> same A/B lines requested within a tight window -> L2 hits + shorter
// vmcnt(0) barrier drains (L2 ~200 cyc vs HBM ~900).
// EPI: 0 = silu -> bf16, 1 = fp32 store (+split-K offset),
//      3 = expert-select fp32 store (keep iff route[row] == col>>8).
// ---------------------------------------------------------------------------
__device__ __forceinline__ void stage_tile(const unsigned short* __restrict__ g,
                                           int ldg, unsigned short* lds,
                                           int wave, int lane) {
  // tile = 128 rows x 64 cols bf16; 16 chunks of 8 rows; wave stages 4 chunks.
  // LDS dst for lane i is base + i*16B (wave-uniform base semantics), i.e.
  // row = chunk*8 + i/8, k-block = i%8. Source column is XOR-swizzled so the
  // LDS image holds (m, kb^ (m&7)) -> conflict-free ds_read_b128 later.
  int srow = lane >> 3;
  int scol = ((lane & 7) ^ (srow & 7)) * 8;
#pragma unroll
  for (int c = 0; c < 4; ++c) {
    int chunk = wave * 4 + c;
    const unsigned short* gp = g + (size_t)(chunk * 8 + srow) * ldg + scol;
    unsigned short* lp = lds + chunk * 512;
    __builtin_amdgcn_global_load_lds(
        (const __attribute__((address_space(1))) unsigned int*)(uintptr_t)gp,
        (__attribute__((address_space(3))) unsigned int*)(uintptr_t)lp,
        16, 0, 0);
  }
}

template <int EPI>
__global__ __launch_bounds__(256) void gemm128(
    const unsigned short* __restrict__ A, int lda,
    const unsigned short* __restrict__ B, int ldb,
    void* __restrict__ C, int ldc,
    const int* __restrict__ route, int kLen, long splitStride) {
  __shared__ unsigned short As[128 * 64];
  __shared__ unsigned short Bs[128 * 64];
  const int lane = threadIdx.x & 63;
  const int wave = threadIdx.x >> 6;
  const int wm = wave >> 1, wn = wave & 1;

  // XCD-aware remap (requires gridDim.x*gridDim.y % 8 == 0, gridDim.y % 8 == 0)
  const int gx = gridDim.x, gyd = gridDim.y;
  const int li = blockIdx.x + gx * blockIdx.y;
  const int xcd = li & 7;
  const int slot = li >> 3;
  const int rpx = gyd >> 3;                 // row-tiles per XCD
  const int bxr = slot % gx;
  const int byr = xcd * rpx + slot / gx;

  const long rowBase = (long)byr * 128;
  const long colBase = (long)bxr * 128;
  const int ks = blockIdx.z * kLen;
  const unsigned short* Ap = A + rowBase * lda + ks;
  const unsigned short* Bp = B + colBase * ldb + ks;
  f32x4 acc[4][4] = {};

  for (int kt = 0; kt < kLen; kt += 64) {
    stage_tile(Ap + kt, lda, As, wave, lane);
    stage_tile(Bp + kt, ldb, Bs, wave, lane);
    __syncthreads();
#pragma unroll
    for (int kk = 0; kk < 64; kk += 32) {
      const int kb = (kk >> 3) + (lane >> 4);   // k-block 0..7
      const int sw = kb ^ (lane & 7);           // swizzled k-block
      bf16x8 af[4], bfr[4];
#pragma unroll
      for (int mt = 0; mt < 4; ++mt) {
        int m = wm * 64 + mt * 16 + (lane & 15);
        af[mt] = *(const bf16x8*)&As[m * 64 + sw * 8];
      }
#pragma unroll
      for (int nt = 0; nt < 4; ++nt) {
        int n = wn * 64 + nt * 16 + (lane & 15);
        bfr[nt] = *(const bf16x8*)&Bs[n * 64 + sw * 8];
      }
#pragma unroll
      for (int mt = 0; mt < 4; ++mt)
#pragma unroll
        for (int nt = 0; nt < 4; ++nt)
          acc[mt][nt] = __builtin_amdgcn_mfma_f32_16x16x32_bf16(
              af[mt], bfr[nt], acc[mt][nt], 0, 0, 0);
    }
    __syncthreads();
  }

  // Epilogue. C/D layout (m89-verified): col = lane&15, row = (lane>>4)*4 + r.
  const int rsub = (lane >> 4) * 4;
  const int csub = lane & 15;
#pragma unroll
  for (int mt = 0; mt < 4; ++mt) {
#pragma unroll
    for (int nt = 0; nt < 4; ++nt) {
      long col = colBase + wn * 64 + nt * 16 + csub;
#pragma unroll
      for (int r = 0; r < 4; ++r) {
        long row = rowBase + wm * 64 + mt * 16 + rsub + r;
        float v = acc[mt][nt][r];
        if (EPI == 0) {
          float s = __fdividef(v, 1.0f + __expf(-v));  // silu
          ((unsigned short*)C)[row * ldc + col] = f2bf(s);
        } else if (EPI == 1) {
          ((float*)C + splitStride * blockIdx.z)[row * ldc + col] = v;
        } else {  // EPI == 3: expert-select store into a_sel [TOK][ADP] fp32
          if (route[row] == (int)(col >> 8))
            ((float*)C)[row * ADP + (col & 255)] = v;
        }
      }
    }
  }
}

// ---------------------------------------------------------------------------
// Sum the 4 split-K fp32 partials of A and cast to bf16 (feeds expert GEMM).
// ---------------------------------------------------------------------------
__global__ __launch_bounds__(256) void reduce_cast(
    const float* __restrict__ P, unsigned short* __restrict__ ab) {
  size_t i = ((size_t)blockIdx.x * 256 + threadIdx.x) * 4;
  const size_t stride = (size_t)TOK * ADP;
  float4 p0 = *(const float4*)(P + i);
  float4 p1 = *(const float4*)(P + stride + i);
  float4 p2 = *(const float4*)(P + 2 * stride + i);
  float4 p3 = *(const float4*)(P + 3 * stride + i);
  ushort4 o;
  o.x = f2bf(p0.x + p1.x + p2.x + p3.x);
  o.y = f2bf(p0.y + p1.y + p2.y + p3.y);
  o.z = f2bf(p0.z + p1.z + p2.z + p3.z);
  o.w = f2bf(p0.w + p1.w + p2.w + p3.w);
  *(ushort4*)(ab + i) = o;
}

// ---------------------------------------------------------------------------
// Sum the 8 split-K fp32 partials of Wcomb = W_out @ W_proj, scale by 0.1,
// cast bf16, and write into the tail columns [4096..4351] of wob_aug.
// ---------------------------------------------------------------------------
__global__ __launch_bounds__(256) void wcomb_reduce(
    const float* __restrict__ Pw, unsigned short* __restrict__ wob) {
  size_t i = ((size_t)blockIdx.x * 256 + threadIdx.x) * 4;  // over 1024*256
  const size_t stride = (size_t)DEMB * ADP;
  float4 s = *(const float4*)(Pw + i);
#pragma unroll
  for (int k = 1; k < 8; ++k) {
    float4 p = *(const float4*)(Pw + k * stride + i);
    s.x += p.x; s.y += p.y; s.z += p.z; s.w += p.w;
  }
  size_t d = i >> 8, a = i & 255;
  ushort4 o;
  o.x = f2bf(0.1f * s.x); o.y = f2bf(0.1f * s.y);
  o.z = f2bf(0.1f * s.z); o.w = f2bf(0.1f * s.w);
  *(ushort4*)(wob + d * KAUG + HID + a) = o;
}

// ---------------------------------------------------------------------------
// LayerNorm over a_sel rows: one WAVE per token (4 tokens / 256-thread block).
// Writes bf16 a_norm into the tail columns [4096..4351] of H_aug (0 for
// inactive tokens); the 0.1 combine scale is folded into Wcomb.
// ---------------------------------------------------------------------------
__global__ __launch_bounds__(256) void ln_kernel(
    const float* __restrict__ asel, const int* __restrict__ route,
    const float* __restrict__ gamma, const float* __restrict__ beta,
    unsigned short* __restrict__ haug) {
  const int lane = threadIdx.x & 63;
  const int t = blockIdx.x * 4 + (threadIdx.x >> 6);
  const int e = route[t];
  float4 v = *(const float4*)(asel + (size_t)t * ADP + lane * 4);
  float s1 = v.x + v.y + v.z + v.w;
  float s2 = v.x * v.x + v.y * v.y + v.z * v.z + v.w * v.w;
#pragma unroll
  for (int off = 32; off > 0; off >>= 1) {
    s1 += __shfl_down(s1, off);
    s2 += __shfl_down(s2, off);
  }
  s1 = __shfl(s1, 0);
  s2 = __shfl(s2, 0);
  float mu = s1 * (1.0f / ADP);
  float var = s2 * (1.0f / ADP) - mu * mu;
  float rstd = rsqrtf(var + 1e-5f);
  ushort4 o;
  if (e >= 0) {
    float4 g = *(const float4*)(gamma + (size_t)e * ADP + lane * 4);
    float4 b = *(const float4*)(beta + (size_t)e * ADP + lane * 4);
    o.x = f2bf((v.x - mu) * rstd * g.x + b.x);
    o.y = f2bf((v.y - mu) * rstd * g.y + b.y);
    o.z = f2bf((v.z - mu) * rstd * g.z + b.z);
    o.w = f2bf((v.w - mu) * rstd * g.w + b.w);
  } else {
    o.x = o.y = o.z = o.w = 0;
  }
  *(ushort4*)(haug + (size_t)t * KAUG + HID + lane * 4) = o;
}

// ---------------------------------------------------------------------------
extern "C" void kernel_launch(void* const* d_in, const int* in_sizes, int n_in,
                              void* d_out, int out_size, void* d_ws, size_t ws_size,
                              hipStream_t stream) {
  const float* x     = (const float*)d_in[0];
  const float* ew    = (const float*)d_in[1];
  const float* W_up  = (const float*)d_in[2];
  const float* W_ad  = (const float*)d_in[3];
  const float* W_ex  = (const float*)d_in[4];
  const float* gam   = (const float*)d_in[5];
  const float* bet   = (const float*)d_in[6];
  const float* W_pr  = (const float*)d_in[7];
  const float* W_out = (const float*)d_in[8];
  float* out = (float*)d_out;

  // workspace layout (~150 MiB total)
  char* ws = (char*)d_ws;
  size_t off = 0;
  auto alloc = [&](size_t n) {
    char* p = ws + off;
    off += (n + 255) & ~(size_t)255;
    return p;
  };
  unsigned short* xb   = (unsigned short*)alloc((size_t)TOK * DEMB * 2);
  unsigned short* wub  = (unsigned short*)alloc((size_t)HID * DEMB * 2);
  unsigned short* wob  = (unsigned short*)alloc((size_t)DEMB * KAUG * 2);  // [Wout | Wcomb]
  unsigned short* wab  = (unsigned short*)alloc((size_t)ADP * HID * 2);
  unsigned short* web  = (unsigned short*)alloc((size_t)NEXP * ADP * ADP * 2);
  unsigned short* wpT  = (unsigned short*)alloc((size_t)ADP * HID * 2);    // Wproj^T bf16
  unsigned short* Haug = (unsigned short*)alloc((size_t)TOK * KAUG * 2);   // [H | anorm]
  float*          P    = (float*)alloc((size_t)4 * TOK * ADP * 4);
  float*          Pw   = (float*)alloc((size_t)8 * DEMB * ADP * 4);
  unsigned short* ab   = (unsigned short*)alloc((size_t)TOK * ADP * 2);
  int*          route  = (int*)alloc((size_t)TOK * 4);
  // a_sel aliases P: P fully consumed by reduce_cast before gemm128<3> writes.
  float* asel = P;

  // 1) bf16 conversion of x + weights (wout strided into wob_aug) + routing
  convert_all<<<8992, 256, 0, stream>>>(x, W_up, W_out, W_ad, W_ex, ew,
                                        xb, wub, wob, wab, web, route);
  // 1b) Wproj^T bf16
  wp_transpose<<<dim3(HID / 64, ADP / 64), 256, 0, stream>>>(W_pr, wpT);
  // 1c) Wcomb = W_out @ W_proj (split-K=8 fp32 partials) -> 0.1x bf16 tail of wob
  gemm128<1><<<dim3(ADP / 128, DEMB / 128, 8), 256, 0, stream>>>(
      wob, KAUG, wpT, HID, Pw, ADP, nullptr, HID / 8, (long)DEMB * ADP);
  wcomb_reduce<<<DEMB * ADP / 1024, 256, 0, stream>>>(Pw, wob);
  // 3) H = silu(x @ W_up^T) into cols [0,4096) of H_aug
  gemm128<0><<<dim3(HID / 128, TOK / 128, 1), 256, 0, stream>>>(
      xb, DEMB, wub, DEMB, Haug, KAUG, nullptr, DEMB, 0);
  // 4) A = H @ W_adapt^T (split-K=4 partials)  [8192,256] K=4096
  gemm128<1><<<dim3(ADP / 128, TOK / 128, 4), 256, 0, stream>>>(
      Haug, KAUG, wab, HID, P, ADP, nullptr, HID / 4, (long)TOK * ADP);
  // 5a) a = sum partials -> bf16
  reduce_cast<<<TOK * ADP / 1024, 256, 0, stream>>>(P, ab);
  // 5b) a_all = a @ W_all^T for all 8 experts; keep winning slice -> a_sel
  gemm128<3><<<dim3(NEXP * ADP / 128, TOK / 128, 1), 256, 0, stream>>>(
      ab, ADP, web, ADP, asel, ADP, route, ADP, 0);
  // 5c) LayerNorm per token -> bf16 into tail cols of H_aug
  ln_kernel<<<TOK / 4, 256, 0, stream>>>(asel, route, gam, bet, Haug);
  // 7) out = H_aug @ [Wout | Wcomb]^T, K=4352
  //    == shared_out + 0.1*combined (gemm<2> eliminated by K-augmentation)
  gemm128<1><<<dim3(DEMB / 128, TOK / 128, 1), 256, 0, stream>>>(
      Haug, KAUG, wob, KAUG, out, DEMB, nullptr, KAUG, 0);
}

// Round 6
// 346.191 us; speedup vs baseline: 1.5448x; 1.0853x over previous
//
#include <hip/hip_runtime.h>
#include <cstdint>

// Problem constants (fixed by reference: B=4, S=2048)
#define TOK  8192   // B*S
#define DEMB 1024   // N_EMBD
#define HID  4096   // HIDDEN
#define ADP  256    // ADAPT
#define NEXP 8
#define KAUG 4352   // HID + ADP (K-augmented out-proj)

typedef __bf16 bf16x8 __attribute__((ext_vector_type(8)));
typedef float  f32x4  __attribute__((ext_vector_type(4)));

__device__ __forceinline__ unsigned short f2bf(float f) {
  // round-to-nearest-even fp32 -> bf16 (matches numpy/jax cast for normal values)
  unsigned int u = __float_as_uint(f);
  u += 0x7fffu + ((u >> 16) & 1u);
  return (unsigned short)(u >> 16);
}
__device__ __forceinline__ float bf2f(unsigned short b) {
  return __uint_as_float(((unsigned int)b) << 16);
}

// ---------------------------------------------------------------------------
// fp32 -> bf16 conversion for x and weights + routing + Wproj transpose, one
// kernel (block-range dispatch). Blocks:
//   [0,8960)    : 2048-elem conversion chunks (x, wup, wout->strided, wadapt, wexp)
//   [8960,8992) : routing (last active expert, -1 if none)
//   [8992,9248) : transpose-convert W_proj [4096,256] fp32 -> wpT [256,4096] bf16
// ---------------------------------------------------------------------------
__global__ __launch_bounds__(256) void convert_all(
    const float* __restrict__ x, const float* __restrict__ wup,
    const float* __restrict__ wout, const float* __restrict__ wadapt,
    const float* __restrict__ wexp, const float* __restrict__ ew,
    const float* __restrict__ wp,
    unsigned short* __restrict__ xb, unsigned short* __restrict__ wub,
    unsigned short* __restrict__ wob, unsigned short* __restrict__ wab,
    unsigned short* __restrict__ web, int* __restrict__ route,
    unsigned short* __restrict__ wpT) {
  __shared__ float tile[64][65];  // only used by transpose blocks
  int b = blockIdx.x;
  if (b >= 8992) {  // Wproj transpose: 64x64 LDS tiles, pad 65 (2-way = free)
    int wli = b - 8992;
    const int h0 = (wli & 63) * 64;  // over 4096
    const int a0 = (wli >> 6) * 64;  // over 256
    const int t = threadIdx.x;
    const int r = t >> 4;            // 0..15
    const int c = (t & 15) * 4;      // 0..60
#pragma unroll
    for (int p = 0; p < 4; ++p) {
      int row = p * 16 + r;
      float4 v = *(const float4*)(wp + (size_t)(h0 + row) * ADP + a0 + c);
      tile[c + 0][row] = v.x;
      tile[c + 1][row] = v.y;
      tile[c + 2][row] = v.z;
      tile[c + 3][row] = v.w;
    }
    __syncthreads();
#pragma unroll
    for (int q = 0; q < 2; ++q) {
      int idx = q * 256 + t;
      int al = idx >> 3;             // a local 0..63
      int hg = (idx & 7) * 8;        // h local 0,8,..,56
      unsigned int w0 = (unsigned int)f2bf(tile[al][hg + 0]) |
                        ((unsigned int)f2bf(tile[al][hg + 1]) << 16);
      unsigned int w1 = (unsigned int)f2bf(tile[al][hg + 2]) |
                        ((unsigned int)f2bf(tile[al][hg + 3]) << 16);
      unsigned int w2 = (unsigned int)f2bf(tile[al][hg + 4]) |
                        ((unsigned int)f2bf(tile[al][hg + 5]) << 16);
      unsigned int w3 = (unsigned int)f2bf(tile[al][hg + 6]) |
                        ((unsigned int)f2bf(tile[al][hg + 7]) << 16);
      *(uint4*)(wpT + (size_t)(a0 + al) * HID + h0 + hg) =
          make_uint4(w0, w1, w2, w3);
    }
    return;
  }
  if (b >= 8960) {  // routing
    int t = (b - 8960) * 256 + threadIdx.x;
    const float* p = ew + (size_t)t * NEXP;
    int r = -1;
#pragma unroll
    for (int e = 0; e < NEXP; ++e)
      if (p[e] > 0.f) r = e;
    route[t] = r;
    return;
  }
  const float* src; unsigned short* dst; int lb; bool strided = false;
  if      (b < 4096) { src = x;      dst = xb;  lb = b; }
  else if (b < 6144) { src = wup;    dst = wub; lb = b - 4096; }
  else if (b < 8192) { src = wout;   dst = wob; lb = b - 6144; strided = true; }
  else if (b < 8704) { src = wadapt; dst = wab; lb = b - 8192; }
  else               { src = wexp;   dst = web; lb = b - 8704; }
  size_t base = (size_t)lb * 2048;
#pragma unroll
  for (int h = 0; h < 2; ++h) {
    size_t off = base + (size_t)h * 1024 + (size_t)threadIdx.x * 4;
    float4 v = *(const float4*)(src + off);
    ushort4 o;
    o.x = f2bf(v.x); o.y = f2bf(v.y); o.z = f2bf(v.z); o.w = f2bf(v.w);
    size_t doff = strided ? (off >> 12) * KAUG + (off & 4095) : off;
    *(ushort4*)(dst + doff) = o;
  }
}

// ---------------------------------------------------------------------------
// 128x128x(BK=64) bf16 MFMA GEMM body, C[m,n] = sum_k A[m,k]*B[n,k] (B^T).
// m97 structure: global_load_lds width-16 staging, XOR-swizzled LDS, 4 waves
// in 2x2 grid, 4x4 16x16x32 tiles/wave.
// EPI: 0 = silu -> bf16, 1 = fp32 store (+split-K offset),
//      3 = expert-select fp32 store (keep iff route[row] == col>>8).
// ---------------------------------------------------------------------------
__device__ __forceinline__ void stage_tile(const unsigned short* __restrict__ g,
                                           int ldg, unsigned short* lds,
                                           int wave, int lane) {
  int srow = lane >> 3;
  int scol = ((lane & 7) ^ (srow & 7)) * 8;
#pragma unroll
  for (int c = 0; c < 4; ++c) {
    int chunk = wave * 4 + c;
    const unsigned short* gp = g + (size_t)(chunk * 8 + srow) * ldg + scol;
    unsigned short* lp = lds + chunk * 512;
    __builtin_amdgcn_global_load_lds(
        (const __attribute__((address_space(1))) unsigned int*)(uintptr_t)gp,
        (__attribute__((address_space(3))) unsigned int*)(uintptr_t)lp,
        16, 0, 0);
  }
}

// XCD-aware remap: raw round-robin puts one N-strip per XCD and streams all
// of A through every XCD. Remap gives each XCD a contiguous band of gy/8
// row-tiles with all col-tiles co-resident (requires gy % 8 == 0).
__device__ __forceinline__ void remap_xcd(int li, int gx, int gy,
                                          int& bx, int& by) {
  int xcd = li & 7;
  int slot = li >> 3;
  bx = slot % gx;
  by = xcd * (gy >> 3) + slot / gx;
}

template <int EPI>
__device__ __forceinline__ void gemm_body(
    int bxr, int byr, int bz,
    const unsigned short* __restrict__ A, int lda,
    const unsigned short* __restrict__ B, int ldb,
    void* __restrict__ C, int ldc,
    const int* __restrict__ route, int kLen, long splitStride,
    unsigned short* As, unsigned short* Bs) {
  const int lane = threadIdx.x & 63;
  const int wave = threadIdx.x >> 6;
  const int wm = wave >> 1, wn = wave & 1;
  const long rowBase = (long)byr * 128;
  const long colBase = (long)bxr * 128;
  const int ks = bz * kLen;
  const unsigned short* Ap = A + rowBase * lda + ks;
  const unsigned short* Bp = B + colBase * ldb + ks;
  f32x4 acc[4][4] = {};

  for (int kt = 0; kt < kLen; kt += 64) {
    stage_tile(Ap + kt, lda, As, wave, lane);
    stage_tile(Bp + kt, ldb, Bs, wave, lane);
    __syncthreads();
#pragma unroll
    for (int kk = 0; kk < 64; kk += 32) {
      const int kb = (kk >> 3) + (lane >> 4);   // k-block 0..7
      const int sw = kb ^ (lane & 7);           // swizzled k-block
      bf16x8 af[4], bfr[4];
#pragma unroll
      for (int mt = 0; mt < 4; ++mt) {
        int m = wm * 64 + mt * 16 + (lane & 15);
        af[mt] = *(const bf16x8*)&As[m * 64 + sw * 8];
      }
#pragma unroll
      for (int nt = 0; nt < 4; ++nt) {
        int n = wn * 64 + nt * 16 + (lane & 15);
        bfr[nt] = *(const bf16x8*)&Bs[n * 64 + sw * 8];
      }
#pragma unroll
      for (int mt = 0; mt < 4; ++mt)
#pragma unroll
        for (int nt = 0; nt < 4; ++nt)
          acc[mt][nt] = __builtin_amdgcn_mfma_f32_16x16x32_bf16(
              af[mt], bfr[nt], acc[mt][nt], 0, 0, 0);
    }
    __syncthreads();
  }

  // Epilogue. C/D layout (m89-verified): col = lane&15, row = (lane>>4)*4 + r.
  const int rsub = (lane >> 4) * 4;
  const int csub = lane & 15;
#pragma unroll
  for (int mt = 0; mt < 4; ++mt) {
#pragma unroll
    for (int nt = 0; nt < 4; ++nt) {
      long col = colBase + wn * 64 + nt * 16 + csub;
#pragma unroll
      for (int r = 0; r < 4; ++r) {
        long row = rowBase + wm * 64 + mt * 16 + rsub + r;
        float v = acc[mt][nt][r];
        if (EPI == 0) {
          float s = __fdividef(v, 1.0f + __expf(-v));  // silu
          ((unsigned short*)C)[row * ldc + col] = f2bf(s);
        } else if (EPI == 1) {
          ((float*)C + splitStride * bz)[row * ldc + col] = v;
        } else {  // EPI == 3: expert-select store into a_sel [TOK][ADP] fp32
          if (route[row] == (int)(col >> 8))
            ((float*)C)[row * ADP + (col & 255)] = v;
        }
      }
    }
  }
}

template <int EPI>
__global__ __launch_bounds__(256, 3) void gemm128(
    const unsigned short* __restrict__ A, int lda,
    const unsigned short* __restrict__ B, int ldb,
    void* __restrict__ C, int ldc,
    const int* __restrict__ route, int kLen, long splitStride) {
  __shared__ unsigned short As[128 * 64];
  __shared__ unsigned short Bs[128 * 64];
  int li = blockIdx.x + gridDim.x * blockIdx.y;
  int bx, by;
  remap_xcd(li, gridDim.x, gridDim.y, bx, by);
  gemm_body<EPI>(bx, by, blockIdx.z, A, lda, B, ldb, C, ldc, route, kLen,
                 splitStride, As, Bs);
}

// ---------------------------------------------------------------------------
// Dual GEMM launch (both EPI=1): blocks [0,nb0) run grid0 (gx0,gy0,z), blocks
// [nb0,..) run grid1. Used to hide the tiny Wcomb split-K GEMM (128 blocks,
// 3/4-idle GPU as its own launch) inside the adapt split-K launch's spare CUs.
// ---------------------------------------------------------------------------
__global__ __launch_bounds__(256, 3) void gemm_dual(
    const unsigned short* __restrict__ A0, int lda0,
    const unsigned short* __restrict__ B0, int ldb0,
    float* __restrict__ C0, int ldc0, int kLen0, long ss0, int gx0, int gy0,
    int nb0,
    const unsigned short* __restrict__ A1, int lda1,
    const unsigned short* __restrict__ B1, int ldb1,
    float* __restrict__ C1, int ldc1, int kLen1, long ss1, int gx1, int gy1) {
  __shared__ unsigned short As[128 * 64];
  __shared__ unsigned short Bs[128 * 64];
  int li = blockIdx.x;
  if (li < nb0) {
    int per = gx0 * gy0;
    int z = li / per, rem = li % per;
    int bx, by;
    remap_xcd(rem, gx0, gy0, bx, by);
    gemm_body<1>(bx, by, z, A0, lda0, B0, ldb0, C0, ldc0, nullptr, kLen0, ss0,
                 As, Bs);
  } else {
    int wli = li - nb0;
    int per = gx1 * gy1;
    int z = wli / per, rem = wli % per;
    int bx, by;
    remap_xcd(rem, gx1, gy1, bx, by);
    gemm_body<1>(bx, by, z, A1, lda1, B1, ldb1, C1, ldc1, nullptr, kLen1, ss1,
                 As, Bs);
  }
}

// ---------------------------------------------------------------------------
// Merged elementwise reductions (block-range dispatch):
//   [0,2048)    : sum 4 split-K fp32 partials of A -> bf16 ab
//   [2048,2304) : sum 8 split-K fp32 partials of Wcomb, x0.1 -> bf16 tail of wob
// ---------------------------------------------------------------------------
__global__ __launch_bounds__(256) void reduce_both(
    const float* __restrict__ P, unsigned short* __restrict__ ab,
    const float* __restrict__ Pw, unsigned short* __restrict__ wob) {
  int b = blockIdx.x;
  if (b < 2048) {
    size_t i = ((size_t)b * 256 + threadIdx.x) * 4;
    const size_t stride = (size_t)TOK * ADP;
    float4 p0 = *(const float4*)(P + i);
    float4 p1 = *(const float4*)(P + stride + i);
    float4 p2 = *(const float4*)(P + 2 * stride + i);
    float4 p3 = *(const float4*)(P + 3 * stride + i);
    ushort4 o;
    o.x = f2bf(p0.x + p1.x + p2.x + p3.x);
    o.y = f2bf(p0.y + p1.y + p2.y + p3.y);
    o.z = f2bf(p0.z + p1.z + p2.z + p3.z);
    o.w = f2bf(p0.w + p1.w + p2.w + p3.w);
    *(ushort4*)(ab + i) = o;
  } else {
    size_t i = ((size_t)(b - 2048) * 256 + threadIdx.x) * 4;  // over 1024*256
    const size_t stride = (size_t)DEMB * ADP;
    float4 s = *(const float4*)(Pw + i);
#pragma unroll
    for (int k = 1; k < 8; ++k) {
      float4 p = *(const float4*)(Pw + k * stride + i);
      s.x += p.x; s.y += p.y; s.z += p.z; s.w += p.w;
    }
    size_t d = i >> 8, a = i & 255;
    ushort4 o;
    o.x = f2bf(0.1f * s.x); o.y = f2bf(0.1f * s.y);
    o.z = f2bf(0.1f * s.z); o.w = f2bf(0.1f * s.w);
    *(ushort4*)(wob + d * KAUG + HID + a) = o;
  }
}

// ---------------------------------------------------------------------------
// LayerNorm over a_sel rows: one WAVE per token (4 tokens / 256-thread block).
// Writes bf16 a_norm into the tail columns [4096..4351] of H_aug (0 for
// inactive tokens); the 0.1 combine scale is folded into Wcomb.
// ---------------------------------------------------------------------------
__global__ __launch_bounds__(256) void ln_kernel(
    const float* __restrict__ asel, const int* __restrict__ route,
    const float* __restrict__ gamma, const float* __restrict__ beta,
    unsigned short* __restrict__ haug) {
  const int lane = threadIdx.x & 63;
  const int t = blockIdx.x * 4 + (threadIdx.x >> 6);
  const int e = route[t];
  float4 v = *(const float4*)(asel + (size_t)t * ADP + lane * 4);
  float s1 = v.x + v.y + v.z + v.w;
  float s2 = v.x * v.x + v.y * v.y + v.z * v.z + v.w * v.w;
#pragma unroll
  for (int off = 32; off > 0; off >>= 1) {
    s1 += __shfl_down(s1, off);
    s2 += __shfl_down(s2, off);
  }
  s1 = __shfl(s1, 0);
  s2 = __shfl(s2, 0);
  float mu = s1 * (1.0f / ADP);
  float var = s2 * (1.0f / ADP) - mu * mu;
  float rstd = rsqrtf(var + 1e-5f);
  ushort4 o;
  if (e >= 0) {
    float4 g = *(const float4*)(gamma + (size_t)e * ADP + lane * 4);
    float4 b = *(const float4*)(beta + (size_t)e * ADP + lane * 4);
    o.x = f2bf((v.x - mu) * rstd * g.x + b.x);
    o.y = f2bf((v.y - mu) * rstd * g.y + b.y);
    o.z = f2bf((v.z - mu) * rstd * g.z + b.z);
    o.w = f2bf((v.w - mu) * rstd * g.w + b.w);
  } else {
    o.x = o.y = o.z = o.w = 0;
  }
  *(ushort4*)(haug + (size_t)t * KAUG + HID + lane * 4) = o;
}

// ---------------------------------------------------------------------------
extern "C" void kernel_launch(void* const* d_in, const int* in_sizes, int n_in,
                              void* d_out, int out_size, void* d_ws, size_t ws_size,
                              hipStream_t stream) {
  const float* x     = (const float*)d_in[0];
  const float* ew    = (const float*)d_in[1];
  const float* W_up  = (const float*)d_in[2];
  const float* W_ad  = (const float*)d_in[3];
  const float* W_ex  = (const float*)d_in[4];
  const float* gam   = (const float*)d_in[5];
  const float* bet   = (const float*)d_in[6];
  const float* W_pr  = (const float*)d_in[7];
  const float* W_out = (const float*)d_in[8];
  float* out = (float*)d_out;

  // workspace layout (~150 MiB total)
  char* ws = (char*)d_ws;
  size_t off = 0;
  auto alloc = [&](size_t n) {
    char* p = ws + off;
    off += (n + 255) & ~(size_t)255;
    return p;
  };
  unsigned short* xb   = (unsigned short*)alloc((size_t)TOK * DEMB * 2);
  unsigned short* wub  = (unsigned short*)alloc((size_t)HID * DEMB * 2);
  unsigned short* wob  = (unsigned short*)alloc((size_t)DEMB * KAUG * 2);  // [Wout | Wcomb]
  unsigned short* wab  = (unsigned short*)alloc((size_t)ADP * HID * 2);
  unsigned short* web  = (unsigned short*)alloc((size_t)NEXP * ADP * ADP * 2);
  unsigned short* wpT  = (unsigned short*)alloc((size_t)ADP * HID * 2);    // Wproj^T bf16
  unsigned short* Haug = (unsigned short*)alloc((size_t)TOK * KAUG * 2);   // [H | anorm]
  float*          P    = (float*)alloc((size_t)4 * TOK * ADP * 4);
  float*          Pw   = (float*)alloc((size_t)8 * DEMB * ADP * 4);
  unsigned short* ab   = (unsigned short*)alloc((size_t)TOK * ADP * 2);
  int*          route  = (int*)alloc((size_t)TOK * 4);
  // a_sel aliases P: P fully consumed by reduce_both before gemm128<3> writes.
  float* asel = P;

  // 1) bf16 conversion of x + weights + routing + Wproj^T  (one launch)
  convert_all<<<9248, 256, 0, stream>>>(x, W_up, W_out, W_ad, W_ex, ew, W_pr,
                                        xb, wub, wob, wab, web, route, wpT);
  // 2) H = silu(x @ W_up^T) into cols [0,4096) of H_aug
  gemm128<0><<<dim3(HID / 128, TOK / 128, 1), 256, 0, stream>>>(
      xb, DEMB, wub, DEMB, Haug, KAUG, nullptr, DEMB, 0);
  // 3) dual: A = H @ W_adapt^T (split-K=4, 512 blocks)
  //        + Wcomb = W_out @ W_proj (split-K=8, 128 blocks) in one launch
  gemm_dual<<<640, 256, 0, stream>>>(
      Haug, KAUG, wab, HID, P, ADP, HID / 4, (long)TOK * ADP, 2, 64, 512,
      wob, KAUG, wpT, HID, Pw, ADP, HID / 8, (long)DEMB * ADP, 2, 8);
  // 4) merged reductions: a partials -> bf16 ab; Wcomb partials -> wob tail
  reduce_both<<<2304, 256, 0, stream>>>(P, ab, Pw, wob);
  // 5) a_all = a @ W_all^T for all 8 experts; keep winning slice -> a_sel
  gemm128<3><<<dim3(NEXP * ADP / 128, TOK / 128, 1), 256, 0, stream>>>(
      ab, ADP, web, ADP, asel, ADP, route, ADP, 0);
  // 6) LayerNorm per token -> bf16 into tail cols of H_aug
  ln_kernel<<<TOK / 4, 256, 0, stream>>>(asel, route, gam, bet, Haug);
  // 7) out = H_aug @ [Wout | Wcomb]^T, K=4352
  //    == shared_out + 0.1*combined (combine folded via K-augmentation)
  gemm128<1><<<dim3(DEMB / 128, TOK / 128, 1), 256, 0, stream>>>(
      Haug, KAUG, wob, KAUG, out, DEMB, nullptr, KAUG, 0);
}